// Round 1
// baseline (3328.283 us; speedup 1.0000x reference)
//
#include <hip/hip_runtime.h>
#include <cmath>

#define ALPHA 0.5f

// ============================================================================
// Encoder: 5x (conv3x3 s2 p1 + ReLU) fused, one block per image (4096 images).
// LDS: img 4KB + a1 32KB + a2 8KB + a3 4KB + a4 1KB + red5 1KB = ~51KB.
// ============================================================================
__global__ __launch_bounds__(256) void enc_fused(
    const float* __restrict__ x,
    const float* __restrict__ w1, const float* __restrict__ b1,
    const float* __restrict__ w2, const float* __restrict__ b2,
    const float* __restrict__ w3, const float* __restrict__ b3,
    const float* __restrict__ w4, const float* __restrict__ b4,
    const float* __restrict__ w5, const float* __restrict__ b5,
    float* __restrict__ hout)
{
    __shared__ float img[1024];      // 1 x 32x32
    __shared__ float a1[32 * 256];   // 32 x 16x16
    __shared__ float a2[32 * 64];    // 32 x 8x8
    __shared__ float a3[64 * 16];    // 64 x 4x4
    __shared__ float a4[64 * 4];     // 64 x 2x2
    __shared__ float red5[4 * 64];

    const int n = blockIdx.x;
    const int tid = threadIdx.x;

    const float* xi = x + n * 1024;
    #pragma unroll
    for (int i = 0; i < 4; i++) img[tid + 256 * i] = xi[tid + 256 * i];
    __syncthreads();

    // conv1: 1->32, 32x32 -> 16x16. thread = pixel, loops all 32 channels.
    {
        const int oy = tid >> 4, ox = tid & 15;
        float patch[9];
        #pragma unroll
        for (int ky = 0; ky < 3; ky++)
            #pragma unroll
            for (int kx = 0; kx < 3; kx++) {
                int iy = 2 * oy - 1 + ky, ix = 2 * ox - 1 + kx;
                patch[ky * 3 + kx] = (iy >= 0 && ix >= 0) ? img[iy * 32 + ix] : 0.f;
            }
        for (int c = 0; c < 32; c++) {
            float acc = b1[c];
            #pragma unroll
            for (int k = 0; k < 9; k++) acc = fmaf(patch[k], w1[c * 9 + k], acc);
            a1[c * 256 + tid] = fmaxf(acc, 0.f);
        }
    }
    __syncthreads();

    // conv2: 32->32, 16x16 -> 8x8. wave-uniform c0 = tid>>6, 8 channels/thread.
    {
        const int p = tid & 63, oy = p >> 3, ox = p & 7;
        const int c0 = tid >> 6;
        float acc[8];
        #pragma unroll
        for (int r = 0; r < 8; r++) acc[r] = b2[c0 + 4 * r];
        for (int ci = 0; ci < 32; ci++) {
            float patch[9];
            #pragma unroll
            for (int ky = 0; ky < 3; ky++)
                #pragma unroll
                for (int kx = 0; kx < 3; kx++) {
                    int iy = 2 * oy - 1 + ky, ix = 2 * ox - 1 + kx;
                    patch[ky * 3 + kx] = (iy >= 0 && ix >= 0) ? a1[ci * 256 + iy * 16 + ix] : 0.f;
                }
            #pragma unroll
            for (int r = 0; r < 8; r++) {
                const float* wp = w2 + ((c0 + 4 * r) * 32 + ci) * 9;
                float t = 0.f;
                #pragma unroll
                for (int k = 0; k < 9; k++) t = fmaf(patch[k], wp[k], t);
                acc[r] += t;
            }
        }
        #pragma unroll
        for (int r = 0; r < 8; r++) a2[(c0 + 4 * r) * 64 + p] = fmaxf(acc[r], 0.f);
    }
    __syncthreads();

    // conv3: 32->64, 8x8 -> 4x4. 4 channels/thread.
    {
        const int p = tid & 15, oy = p >> 2, ox = p & 3;
        const int c0 = tid >> 4;   // 0..15
        float acc[4];
        #pragma unroll
        for (int r = 0; r < 4; r++) acc[r] = b3[c0 + 16 * r];
        for (int ci = 0; ci < 32; ci++) {
            float patch[9];
            #pragma unroll
            for (int ky = 0; ky < 3; ky++)
                #pragma unroll
                for (int kx = 0; kx < 3; kx++) {
                    int iy = 2 * oy - 1 + ky, ix = 2 * ox - 1 + kx;
                    patch[ky * 3 + kx] = (iy >= 0 && ix >= 0) ? a2[ci * 64 + iy * 8 + ix] : 0.f;
                }
            #pragma unroll
            for (int r = 0; r < 4; r++) {
                const float* wp = w3 + ((c0 + 16 * r) * 32 + ci) * 9;
                float t = 0.f;
                #pragma unroll
                for (int k = 0; k < 9; k++) t = fmaf(patch[k], wp[k], t);
                acc[r] += t;
            }
        }
        #pragma unroll
        for (int r = 0; r < 4; r++) a3[(c0 + 16 * r) * 16 + p] = fmaxf(acc[r], 0.f);
    }
    __syncthreads();

    // conv4: 64->64, 4x4 -> 2x2. one output/thread.
    {
        const int p = tid & 3, oy = p >> 1, ox = p & 1;
        const int c = tid >> 2;
        float acc = b4[c];
        for (int ci = 0; ci < 64; ci++) {
            const float* wp = w4 + (c * 64 + ci) * 9;
            #pragma unroll
            for (int ky = 0; ky < 3; ky++)
                #pragma unroll
                for (int kx = 0; kx < 3; kx++) {
                    int iy = 2 * oy - 1 + ky, ix = 2 * ox - 1 + kx;
                    if (iy >= 0 && ix >= 0)
                        acc = fmaf(a3[ci * 16 + iy * 4 + ix], wp[ky * 3 + kx], acc);
                }
        }
        a4[c * 4 + p] = fmaxf(acc, 0.f);
    }
    __syncthreads();

    // conv5: 64->64, 2x2 -> 1x1. taps (ky,kx) in {1,2}^2, iy=ky-1, ix=kx-1.
    // split ci into 4 parts across tid>>6, reduce in LDS.
    {
        const int c = tid & 63, part = tid >> 6;
        float s = 0.f;
        for (int ci = part * 16; ci < part * 16 + 16; ci++) {
            const float* wp = w5 + (c * 64 + ci) * 9;
            const float* av = a4 + ci * 4;
            s = fmaf(av[0], wp[4], s);
            s = fmaf(av[1], wp[5], s);
            s = fmaf(av[2], wp[7], s);
            s = fmaf(av[3], wp[8], s);
        }
        red5[part * 64 + c] = s;
    }
    __syncthreads();
    if (tid < 64) {
        float v = b5[tid] + red5[tid] + red5[64 + tid] + red5[128 + tid] + red5[192 + tid];
        hout[n * 64 + tid] = fmaxf(v, 0.f);
    }
}

// ============================================================================
// FC heads: out[256, 8192] = h[256,1024] @ [mu|D|B]^T + bias.
// 64x64 tiles, K-tiles of 32, 4x4 microtile/thread. Region boundaries (256,
// 4352) are multiples of 64 so each block touches exactly one weight array.
// ============================================================================
__global__ __launch_bounds__(256) void fc_enc(
    const float* __restrict__ h,
    const float* __restrict__ wmu, const float* __restrict__ bmu,
    const float* __restrict__ wD,  const float* __restrict__ bD,
    const float* __restrict__ wB,  const float* __restrict__ bB,
    float* __restrict__ mu, float* __restrict__ Dv, float* __restrict__ Bv)
{
    __shared__ float As[32][65];
    __shared__ float Bs[32][65];
    const int tid = threadIdx.x;
    const int m0 = blockIdx.y * 64;
    const int n0 = blockIdx.x * 64;

    const float* wbase; const float* bias; float* outp; int stride; int nloc;
    if (n0 < 256)       { wbase = wmu; bias = bmu; outp = mu; stride = 256;  nloc = n0; }
    else if (n0 < 4352) { wbase = wD;  bias = bD;  outp = Dv; stride = 4096; nloc = n0 - 256; }
    else                { wbase = wB;  bias = bB;  outp = Bv; stride = 3840; nloc = n0 - 4352; }

    const int tx = tid & 15, ty = tid >> 4;
    float acc[4][4] = {};
    for (int k0 = 0; k0 < 1024; k0 += 32) {
        #pragma unroll
        for (int s = 0; s < 8; s++) {
            int l = tid + 256 * s;
            int row = l >> 5, kk = l & 31;
            As[kk][row] = h[(m0 + row) * 1024 + k0 + kk];
            Bs[kk][row] = wbase[(nloc + row) * 1024 + k0 + kk];
        }
        __syncthreads();
        #pragma unroll
        for (int kk = 0; kk < 32; kk++) {
            float av[4], bv[4];
            #pragma unroll
            for (int i = 0; i < 4; i++) av[i] = As[kk][ty * 4 + i];
            #pragma unroll
            for (int j = 0; j < 4; j++) bv[j] = Bs[kk][tx * 4 + j];
            #pragma unroll
            for (int i = 0; i < 4; i++)
                #pragma unroll
                for (int j = 0; j < 4; j++) acc[i][j] = fmaf(av[i], bv[j], acc[i][j]);
        }
        __syncthreads();
    }
    #pragma unroll
    for (int i = 0; i < 4; i++) {
        int m = m0 + ty * 4 + i;
        #pragma unroll
        for (int j = 0; j < 4; j++) {
            int nc = nloc + tx * 4 + j;
            outp[m * stride + nc] = acc[i][j] + bias[nc];
        }
    }
}

// ============================================================================
// Pm: block-tridiagonal assembly + alpha*I, written straight to d_out.
// ============================================================================
__global__ __launch_bounds__(256) void build_pm(
    const float* __restrict__ Dv, const float* __restrict__ Bv,
    float* __restrict__ Pm)
{
    const int idx = blockIdx.x * 256 + threadIdx.x;   // 2^24 elements
    const int b = idx >> 16, rem = idx & 65535;
    const int i = rem >> 8, j = rem & 255;
    const int bi = i >> 4, pi = i & 15, bj = j >> 4, pj = j & 15;
    float v = 0.f;
    if (bi == bj) {
        v = Dv[b * 4096 + bi * 256 + pi * 16 + pj];
        if (i == j) v += ALPHA;
    } else if (bi == bj + 1) {
        v = Bv[b * 3840 + bj * 256 + pi * 16 + pj];
    } else if (bj == bi + 1) {
        v = Bv[b * 3840 + bi * 256 + pj * 16 + pi];   // transposed super-diagonal
    }
    Pm[idx] = v;
}

// ============================================================================
// Banded Cholesky. Pm is block-tridiag (16x16 blocks) => lower bandwidth 31,
// and L keeps the band. One wave per sample; lane d handles row j+d of
// column j. Uses only the lower triangle (matches np.linalg.cholesky).
// Band store: Lb[i*32 + (i-k)] = L(i,k). LDS ~63KB.
// ============================================================================
__global__ __launch_bounds__(64) void chol_band(
    const float* __restrict__ Dv, const float* __restrict__ Bv,
    float* __restrict__ Lb_g)
{
    __shared__ float Lb[256 * 32];
    __shared__ float Ds[4096];
    __shared__ float Bs2[3840];
    const int b = blockIdx.x, lane = threadIdx.x;
    for (int i = lane; i < 8192; i += 64) Lb[i] = 0.f;
    for (int i = lane; i < 4096; i += 64) Ds[i] = Dv[b * 4096 + i];
    for (int i = lane; i < 3840; i += 64) Bs2[i] = Bv[b * 3840 + i];
    __syncthreads();

    const int d = lane;
    for (int j = 0; j < 256; j++) {
        const int i = j + d;
        float s = 0.f;
        if (d < 32 && i < 256) {
            // A(i,j) from the block structure (lower triangle only)
            int bi = i >> 4, bj = j >> 4, pi = i & 15, pj = j & 15;
            float a;
            if (bi == bj)           a = Ds[bi * 256 + pi * 16 + pj] + (i == j ? ALPHA : 0.f);
            else if (bi == bj + 1)  a = Bs2[bj * 256 + pi * 16 + pj];
            else                    a = 0.f;
            float s0 = 0.f, s1 = 0.f;
            int kmin = i - 31; if (kmin < 0) kmin = 0;
            int k = kmin;
            for (; k + 1 < j; k += 2) {
                s0 = fmaf(Lb[i * 32 + (i - k)],     Lb[j * 32 + (j - k)],     s0);
                s1 = fmaf(Lb[i * 32 + (i - k - 1)], Lb[j * 32 + (j - k - 1)], s1);
            }
            if (k < j) s0 = fmaf(Lb[i * 32 + (i - k)], Lb[j * 32 + (j - k)], s0);
            s = a - s0 - s1;
        }
        float diag = __shfl(s, 0);      // lane 0: A(j,j) - sum L(j,k)^2
        float Ljj = sqrtf(diag);
        if (d == 0)                  Lb[j * 32] = Ljj;
        else if (d < 32 && i < 256)  Lb[i * 32 + d] = s / Ljj;
        __syncthreads();
    }
    for (int i = lane; i < 8192; i += 64) Lb_g[b * 8192 + i] = Lb[i];
}

// ============================================================================
// cov = inv(L): column j of L^{-1} is an independent forward solve with a
// 32-deep dependency window (L is banded). One thread per column; private
// circular window in LDS; NO barriers. Writes full 256x256 incl. zeros.
// ============================================================================
__global__ __launch_bounds__(256) void inv_band(
    const float* __restrict__ Lb_g, float* __restrict__ cov)
{
    __shared__ float win[32 * 256];    // [slot][column]
    const int b = blockIdx.x, j = threadIdx.x;
    const float* Lb = Lb_g + b * 8192;
    float* covb = cov + (size_t)b * 65536;
    for (int i = 0; i < 256; i++) {
        float Lr[32];
        #pragma unroll
        for (int d = 0; d < 32; d++) Lr[d] = Lb[i * 32 + d];
        float g = 0.f;
        if (i >= j) {
            float s = 0.f;
            #pragma unroll
            for (int d = 1; d < 32; d++) {
                int k = i - d;
                if (k >= j) s = fmaf(Lr[d], win[(k & 31) * 256 + j], s);
            }
            g = ((i == j) ? 1.f - s : -s) / Lr[0];
            win[(i & 31) * 256 + j] = g;
        }
        covb[i * 256 + j] = g;         // coalesced; zeros above diagonal
    }
}

// ============================================================================
// z = mu + cov @ eps (per-sample matvec)
// ============================================================================
__global__ __launch_bounds__(256) void zvec_k(
    const float* __restrict__ cov, const float* __restrict__ mu,
    const float* __restrict__ eps, float* __restrict__ z)
{
    __shared__ float es[256];
    const int b = blockIdx.x, i = threadIdx.x;
    es[i] = eps[b * 256 + i];
    __syncthreads();
    const float4* row = (const float4*)(cov + (size_t)b * 65536 + i * 256);
    float s = 0.f;
    #pragma unroll 8
    for (int k = 0; k < 64; k++) {
        float4 v = row[k];
        s = fmaf(v.x, es[4 * k], s);
        s = fmaf(v.y, es[4 * k + 1], s);
        s = fmaf(v.z, es[4 * k + 2], s);
        s = fmaf(v.w, es[4 * k + 3], s);
    }
    z[b * 256 + i] = mu[b * 256 + i] + s;
}

// ============================================================================
// Decoder FC: hd0[256,1024] = z @ fc_dec_w^T + b  (w: [1024,256])
// ============================================================================
__global__ __launch_bounds__(256) void fc_dec_k(
    const float* __restrict__ z, const float* __restrict__ w,
    const float* __restrict__ bias, float* __restrict__ hd0)
{
    __shared__ float zs[256];
    const int blk = blockIdx.x;
    const int b = blk >> 2;
    const int f = ((blk & 3) << 8) + threadIdx.x;
    zs[threadIdx.x] = z[b * 256 + threadIdx.x];
    __syncthreads();
    const float4* wr = (const float4*)(w + f * 256);
    float s = 0.f;
    #pragma unroll 8
    for (int k = 0; k < 64; k++) {
        float4 v = wr[k];
        s = fmaf(v.x, zs[4 * k], s);
        s = fmaf(v.y, zs[4 * k + 1], s);
        s = fmaf(v.z, zs[4 * k + 2], s);
        s = fmaf(v.w, zs[4 * k + 3], s);
    }
    hd0[b * 1024 + f] = s + bias[f];
}

// ============================================================================
// Decoder: 4x (convT3x3 s2 p1 op1 + ELU) + convT + sigmoid, fused per image.
// Tap rule (derived from the reference's flip+dilation conv):
//   out[oy] += in[iy] * w[ky]  with ky = oy+1-2*iy  (0<=ky<3, 0<=iy<Hin).
// Weight layout [Cin][Cout][3][3]. LDS ~46KB.
// ============================================================================
__device__ __forceinline__ float eluf(float v) { return v > 0.f ? v : expf(v) - 1.f; }

__global__ __launch_bounds__(256) void dec_fused(
    const float* __restrict__ hd0,
    const float* __restrict__ wt5, const float* __restrict__ bt5,
    const float* __restrict__ wt4, const float* __restrict__ bt4,
    const float* __restrict__ wt3, const float* __restrict__ bt3,
    const float* __restrict__ wt2, const float* __restrict__ bt2,
    const float* __restrict__ wt1, const float* __restrict__ bt1,
    float* __restrict__ xr)
{
    __shared__ float d0[64];
    __shared__ float d1[64 * 4];
    __shared__ float d2[64 * 16];
    __shared__ float d3[32 * 64];
    __shared__ float d4[32 * 256];
    const int n = blockIdx.x, tid = threadIdx.x;
    if (tid < 64) d0[tid] = hd0[n * 64 + tid];
    __syncthreads();

    // convT5: 64x1x1 -> 64x2x2 (single tap: ky=oy+1, kx=ox+1, iy=ix=0)
    {
        const int c = tid >> 2, p = tid & 3, oy = p >> 1, ox = p & 1;
        float s = bt5[c];
        for (int ci = 0; ci < 64; ci++)
            s = fmaf(d0[ci], wt5[(ci * 64 + c) * 9 + (oy + 1) * 3 + (ox + 1)], s);
        d1[c * 4 + p] = eluf(s);
    }
    __syncthreads();

    // convT4: 64x2x2 -> 64x4x4
    {
        const int p = tid & 15, oy = p >> 2, ox = p & 3;
        const int c0 = tid >> 4;   // 0..15
        int nky = 0, kys[2], iys[2];
        for (int ky = 0; ky < 3; ky++) { int t = oy + 1 - ky; if (t >= 0 && !(t & 1) && (t >> 1) < 2) { kys[nky] = ky; iys[nky] = t >> 1; nky++; } }
        int nkx = 0, kxs[2], ixs[2];
        for (int kx = 0; kx < 3; kx++) { int t = ox + 1 - kx; if (t >= 0 && !(t & 1) && (t >> 1) < 2) { kxs[nkx] = kx; ixs[nkx] = t >> 1; nkx++; } }
        float acc[4];
        #pragma unroll
        for (int r = 0; r < 4; r++) acc[r] = bt4[c0 + 16 * r];
        for (int ci = 0; ci < 64; ci++)
            for (int a = 0; a < nky; a++)
                for (int e = 0; e < nkx; e++) {
                    float v = d1[ci * 4 + iys[a] * 2 + ixs[e]];
                    int wk = kys[a] * 3 + kxs[e];
                    #pragma unroll
                    for (int r = 0; r < 4; r++)
                        acc[r] = fmaf(v, wt4[(ci * 64 + c0 + 16 * r) * 9 + wk], acc[r]);
                }
        #pragma unroll
        for (int r = 0; r < 4; r++) d2[(c0 + 16 * r) * 16 + p] = eluf(acc[r]);
    }
    __syncthreads();

    // convT3: 64x4x4 -> 32x8x8
    {
        const int p = tid & 63, oy = p >> 3, ox = p & 7;
        const int c0 = tid >> 6;   // 0..3
        int nky = 0, kys[2], iys[2];
        for (int ky = 0; ky < 3; ky++) { int t = oy + 1 - ky; if (t >= 0 && !(t & 1) && (t >> 1) < 4) { kys[nky] = ky; iys[nky] = t >> 1; nky++; } }
        int nkx = 0, kxs[2], ixs[2];
        for (int kx = 0; kx < 3; kx++) { int t = ox + 1 - kx; if (t >= 0 && !(t & 1) && (t >> 1) < 4) { kxs[nkx] = kx; ixs[nkx] = t >> 1; nkx++; } }
        float acc[8];
        #pragma unroll
        for (int r = 0; r < 8; r++) acc[r] = bt3[c0 + 4 * r];
        for (int ci = 0; ci < 64; ci++)
            for (int a = 0; a < nky; a++)
                for (int e = 0; e < nkx; e++) {
                    float v = d2[ci * 16 + iys[a] * 4 + ixs[e]];
                    int wk = kys[a] * 3 + kxs[e];
                    #pragma unroll
                    for (int r = 0; r < 8; r++)
                        acc[r] = fmaf(v, wt3[(ci * 32 + c0 + 4 * r) * 9 + wk], acc[r]);
                }
        #pragma unroll
        for (int r = 0; r < 8; r++) d3[(c0 + 4 * r) * 64 + p] = eluf(acc[r]);
    }
    __syncthreads();

    // convT2: 32x8x8 -> 32x16x16 (thread = pixel, all 32 channels)
    {
        const int oy = tid >> 4, ox = tid & 15;
        int nky = 0, kys[2], iys[2];
        for (int ky = 0; ky < 3; ky++) { int t = oy + 1 - ky; if (t >= 0 && !(t & 1) && (t >> 1) < 8) { kys[nky] = ky; iys[nky] = t >> 1; nky++; } }
        int nkx = 0, kxs[2], ixs[2];
        for (int kx = 0; kx < 3; kx++) { int t = ox + 1 - kx; if (t >= 0 && !(t & 1) && (t >> 1) < 8) { kxs[nkx] = kx; ixs[nkx] = t >> 1; nkx++; } }
        float acc[32];
        #pragma unroll
        for (int r = 0; r < 32; r++) acc[r] = bt2[r];
        for (int ci = 0; ci < 32; ci++)
            for (int a = 0; a < nky; a++)
                for (int e = 0; e < nkx; e++) {
                    float v = d3[ci * 64 + iys[a] * 8 + ixs[e]];
                    int wk = kys[a] * 3 + kxs[e];
                    #pragma unroll
                    for (int r = 0; r < 32; r++)
                        acc[r] = fmaf(v, wt2[(ci * 32 + r) * 9 + wk], acc[r]);
                }
        #pragma unroll
        for (int r = 0; r < 32; r++) d4[r * 256 + tid] = eluf(acc[r]);
    }
    __syncthreads();

    // convT1: 32x16x16 -> 1x32x32, sigmoid, store to d_out
    {
        const float bb = bt1[0];
        #pragma unroll
        for (int q = 0; q < 4; q++) {
            const int px = tid + 256 * q, oy = px >> 5, ox = px & 31;
            int nky = 0, kys[2], iys[2];
            for (int ky = 0; ky < 3; ky++) { int t = oy + 1 - ky; if (t >= 0 && !(t & 1) && (t >> 1) < 16) { kys[nky] = ky; iys[nky] = t >> 1; nky++; } }
            int nkx = 0, kxs[2], ixs[2];
            for (int kx = 0; kx < 3; kx++) { int t = ox + 1 - kx; if (t >= 0 && !(t & 1) && (t >> 1) < 16) { kxs[nkx] = kx; ixs[nkx] = t >> 1; nkx++; } }
            float acc = bb;
            for (int ci = 0; ci < 32; ci++)
                for (int a = 0; a < nky; a++)
                    for (int e = 0; e < nkx; e++)
                        acc = fmaf(d4[ci * 256 + iys[a] * 16 + ixs[e]],
                                   wt1[ci * 9 + kys[a] * 3 + kxs[e]], acc);
            xr[n * 1024 + px] = 1.f / (1.f + expf(-acc));
        }
    }
}

// ============================================================================
extern "C" void kernel_launch(void* const* d_in, const int* in_sizes, int n_in,
                              void* d_out, int out_size, void* d_ws, size_t ws_size,
                              hipStream_t stream)
{
    (void)in_sizes; (void)n_in; (void)out_size; (void)ws_size;
    const float* x    = (const float*)d_in[0];
    const float* eps  = (const float*)d_in[1];
    const float* w1 = (const float*)d_in[2];  const float* b1 = (const float*)d_in[3];
    const float* w2 = (const float*)d_in[4];  const float* b2 = (const float*)d_in[5];
    const float* w3 = (const float*)d_in[6];  const float* b3 = (const float*)d_in[7];
    const float* w4 = (const float*)d_in[8];  const float* b4 = (const float*)d_in[9];
    const float* w5 = (const float*)d_in[10]; const float* b5 = (const float*)d_in[11];
    const float* fc_mu_w = (const float*)d_in[12]; const float* fc_mu_b = (const float*)d_in[13];
    const float* fc_D_w  = (const float*)d_in[14]; const float* fc_D_b  = (const float*)d_in[15];
    const float* fc_B_w  = (const float*)d_in[16]; const float* fc_B_b  = (const float*)d_in[17];
    const float* fc_dec_w = (const float*)d_in[18]; const float* fc_dec_b = (const float*)d_in[19];
    const float* wt5 = (const float*)d_in[20]; const float* bt5 = (const float*)d_in[21];
    const float* wt4 = (const float*)d_in[22]; const float* bt4 = (const float*)d_in[23];
    const float* wt3 = (const float*)d_in[24]; const float* bt3 = (const float*)d_in[25];
    const float* wt2 = (const float*)d_in[26]; const float* bt2 = (const float*)d_in[27];
    const float* wt1 = (const float*)d_in[28]; const float* bt1 = (const float*)d_in[29];

    // workspace layout (floats): total 4,718,592 (= 18.9 MB)
    float* ws  = (float*)d_ws;
    float* h   = ws;                  // 262144  [4096][64]
    float* Dv  = ws + 262144;         // 1048576 [256][4096]
    float* Bv  = ws + 1310720;        // 983040  [256][3840]
    float* Lb  = ws + 2293760;        // 2097152 [256][256][32] band of L
    float* z   = ws + 4390912;        // 65536   [256][256]
    float* hd0 = ws + 4456448;        // 262144  [4096][64]

    // output layout: xr | mu | cov | Pm
    float* out = (float*)d_out;
    float* xr  = out;                 // 4194304
    float* mu  = out + 4194304;       // 65536
    float* cov = out + 4259840;       // 16777216
    float* Pm  = out + 21037056;      // 16777216

    enc_fused<<<4096, 256, 0, stream>>>(x, w1, b1, w2, b2, w3, b3, w4, b4, w5, b5, h);
    fc_enc<<<dim3(128, 4), 256, 0, stream>>>(h, fc_mu_w, fc_mu_b, fc_D_w, fc_D_b,
                                             fc_B_w, fc_B_b, mu, Dv, Bv);
    build_pm<<<65536, 256, 0, stream>>>(Dv, Bv, Pm);
    chol_band<<<256, 64, 0, stream>>>(Dv, Bv, Lb);
    inv_band<<<256, 256, 0, stream>>>(Lb, cov);
    zvec_k<<<256, 256, 0, stream>>>(cov, mu, eps, z);
    fc_dec_k<<<1024, 256, 0, stream>>>(z, fc_dec_w, fc_dec_b, hd0);
    dec_fused<<<4096, 256, 0, stream>>>(hd0, wt5, bt5, wt4, bt4, wt3, bt3,
                                        wt2, bt2, wt1, bt1, xr);
}

// Round 2
// 2350.112 us; speedup vs baseline: 1.4162x; 1.4162x over previous
//
#include <hip/hip_runtime.h>
#include <cmath>

#define ALPHA 0.5f

// ============================================================================
// Encoder: 5x (conv3x3 s2 p1 + ReLU) fused, one block per image (4096 images).
// (unchanged from R1)
// ============================================================================
__global__ __launch_bounds__(256) void enc_fused(
    const float* __restrict__ x,
    const float* __restrict__ w1, const float* __restrict__ b1,
    const float* __restrict__ w2, const float* __restrict__ b2,
    const float* __restrict__ w3, const float* __restrict__ b3,
    const float* __restrict__ w4, const float* __restrict__ b4,
    const float* __restrict__ w5, const float* __restrict__ b5,
    float* __restrict__ hout)
{
    __shared__ float img[1024];
    __shared__ float a1[32 * 256];
    __shared__ float a2[32 * 64];
    __shared__ float a3[64 * 16];
    __shared__ float a4[64 * 4];
    __shared__ float red5[4 * 64];

    const int n = blockIdx.x;
    const int tid = threadIdx.x;

    const float* xi = x + n * 1024;
    #pragma unroll
    for (int i = 0; i < 4; i++) img[tid + 256 * i] = xi[tid + 256 * i];
    __syncthreads();

    // conv1: 1->32, 32x32 -> 16x16
    {
        const int oy = tid >> 4, ox = tid & 15;
        float patch[9];
        #pragma unroll
        for (int ky = 0; ky < 3; ky++)
            #pragma unroll
            for (int kx = 0; kx < 3; kx++) {
                int iy = 2 * oy - 1 + ky, ix = 2 * ox - 1 + kx;
                patch[ky * 3 + kx] = (iy >= 0 && ix >= 0) ? img[iy * 32 + ix] : 0.f;
            }
        for (int c = 0; c < 32; c++) {
            float acc = b1[c];
            #pragma unroll
            for (int k = 0; k < 9; k++) acc = fmaf(patch[k], w1[c * 9 + k], acc);
            a1[c * 256 + tid] = fmaxf(acc, 0.f);
        }
    }
    __syncthreads();

    // conv2: 32->32, 16x16 -> 8x8
    {
        const int p = tid & 63, oy = p >> 3, ox = p & 7;
        const int c0 = tid >> 6;
        float acc[8];
        #pragma unroll
        for (int r = 0; r < 8; r++) acc[r] = b2[c0 + 4 * r];
        for (int ci = 0; ci < 32; ci++) {
            float patch[9];
            #pragma unroll
            for (int ky = 0; ky < 3; ky++)
                #pragma unroll
                for (int kx = 0; kx < 3; kx++) {
                    int iy = 2 * oy - 1 + ky, ix = 2 * ox - 1 + kx;
                    patch[ky * 3 + kx] = (iy >= 0 && ix >= 0) ? a1[ci * 256 + iy * 16 + ix] : 0.f;
                }
            #pragma unroll
            for (int r = 0; r < 8; r++) {
                const float* wp = w2 + ((c0 + 4 * r) * 32 + ci) * 9;
                float t = 0.f;
                #pragma unroll
                for (int k = 0; k < 9; k++) t = fmaf(patch[k], wp[k], t);
                acc[r] += t;
            }
        }
        #pragma unroll
        for (int r = 0; r < 8; r++) a2[(c0 + 4 * r) * 64 + p] = fmaxf(acc[r], 0.f);
    }
    __syncthreads();

    // conv3: 32->64, 8x8 -> 4x4
    {
        const int p = tid & 15, oy = p >> 2, ox = p & 3;
        const int c0 = tid >> 4;
        float acc[4];
        #pragma unroll
        for (int r = 0; r < 4; r++) acc[r] = b3[c0 + 16 * r];
        for (int ci = 0; ci < 32; ci++) {
            float patch[9];
            #pragma unroll
            for (int ky = 0; ky < 3; ky++)
                #pragma unroll
                for (int kx = 0; kx < 3; kx++) {
                    int iy = 2 * oy - 1 + ky, ix = 2 * ox - 1 + kx;
                    patch[ky * 3 + kx] = (iy >= 0 && ix >= 0) ? a2[ci * 64 + iy * 8 + ix] : 0.f;
                }
            #pragma unroll
            for (int r = 0; r < 4; r++) {
                const float* wp = w3 + ((c0 + 16 * r) * 32 + ci) * 9;
                float t = 0.f;
                #pragma unroll
                for (int k = 0; k < 9; k++) t = fmaf(patch[k], wp[k], t);
                acc[r] += t;
            }
        }
        #pragma unroll
        for (int r = 0; r < 4; r++) a3[(c0 + 16 * r) * 16 + p] = fmaxf(acc[r], 0.f);
    }
    __syncthreads();

    // conv4: 64->64, 4x4 -> 2x2
    {
        const int p = tid & 3, oy = p >> 1, ox = p & 1;
        const int c = tid >> 2;
        float acc = b4[c];
        for (int ci = 0; ci < 64; ci++) {
            const float* wp = w4 + (c * 64 + ci) * 9;
            #pragma unroll
            for (int ky = 0; ky < 3; ky++)
                #pragma unroll
                for (int kx = 0; kx < 3; kx++) {
                    int iy = 2 * oy - 1 + ky, ix = 2 * ox - 1 + kx;
                    if (iy >= 0 && ix >= 0)
                        acc = fmaf(a3[ci * 16 + iy * 4 + ix], wp[ky * 3 + kx], acc);
                }
        }
        a4[c * 4 + p] = fmaxf(acc, 0.f);
    }
    __syncthreads();

    // conv5: 64->64, 2x2 -> 1x1
    {
        const int c = tid & 63, part = tid >> 6;
        float s = 0.f;
        for (int ci = part * 16; ci < part * 16 + 16; ci++) {
            const float* wp = w5 + (c * 64 + ci) * 9;
            const float* av = a4 + ci * 4;
            s = fmaf(av[0], wp[4], s);
            s = fmaf(av[1], wp[5], s);
            s = fmaf(av[2], wp[7], s);
            s = fmaf(av[3], wp[8], s);
        }
        red5[part * 64 + c] = s;
    }
    __syncthreads();
    if (tid < 64) {
        float v = b5[tid] + red5[tid] + red5[64 + tid] + red5[128 + tid] + red5[192 + tid];
        hout[n * 64 + tid] = fmaxf(v, 0.f);
    }
}

// ============================================================================
// FC heads (unchanged)
// ============================================================================
__global__ __launch_bounds__(256) void fc_enc(
    const float* __restrict__ h,
    const float* __restrict__ wmu, const float* __restrict__ bmu,
    const float* __restrict__ wD,  const float* __restrict__ bD,
    const float* __restrict__ wB,  const float* __restrict__ bB,
    float* __restrict__ mu, float* __restrict__ Dv, float* __restrict__ Bv)
{
    __shared__ float As[32][65];
    __shared__ float Bs[32][65];
    const int tid = threadIdx.x;
    const int m0 = blockIdx.y * 64;
    const int n0 = blockIdx.x * 64;

    const float* wbase; const float* bias; float* outp; int stride; int nloc;
    if (n0 < 256)       { wbase = wmu; bias = bmu; outp = mu; stride = 256;  nloc = n0; }
    else if (n0 < 4352) { wbase = wD;  bias = bD;  outp = Dv; stride = 4096; nloc = n0 - 256; }
    else                { wbase = wB;  bias = bB;  outp = Bv; stride = 3840; nloc = n0 - 4352; }

    const int tx = tid & 15, ty = tid >> 4;
    float acc[4][4] = {};
    for (int k0 = 0; k0 < 1024; k0 += 32) {
        #pragma unroll
        for (int s = 0; s < 8; s++) {
            int l = tid + 256 * s;
            int row = l >> 5, kk = l & 31;
            As[kk][row] = h[(m0 + row) * 1024 + k0 + kk];
            Bs[kk][row] = wbase[(nloc + row) * 1024 + k0 + kk];
        }
        __syncthreads();
        #pragma unroll
        for (int kk = 0; kk < 32; kk++) {
            float av[4], bv[4];
            #pragma unroll
            for (int i = 0; i < 4; i++) av[i] = As[kk][ty * 4 + i];
            #pragma unroll
            for (int j = 0; j < 4; j++) bv[j] = Bs[kk][tx * 4 + j];
            #pragma unroll
            for (int i = 0; i < 4; i++)
                #pragma unroll
                for (int j = 0; j < 4; j++) acc[i][j] = fmaf(av[i], bv[j], acc[i][j]);
        }
        __syncthreads();
    }
    #pragma unroll
    for (int i = 0; i < 4; i++) {
        int m = m0 + ty * 4 + i;
        #pragma unroll
        for (int j = 0; j < 4; j++) {
            int nc = nloc + tx * 4 + j;
            outp[m * stride + nc] = acc[i][j] + bias[nc];
        }
    }
}

// ============================================================================
// Pm assembly (unchanged)
// ============================================================================
__global__ __launch_bounds__(256) void build_pm(
    const float* __restrict__ Dv, const float* __restrict__ Bv,
    float* __restrict__ Pm)
{
    const int idx = blockIdx.x * 256 + threadIdx.x;
    const int b = idx >> 16, rem = idx & 65535;
    const int i = rem >> 8, j = rem & 255;
    const int bi = i >> 4, pi = i & 15, bj = j >> 4, pj = j & 15;
    float v = 0.f;
    if (bi == bj) {
        v = Dv[b * 4096 + bi * 256 + pi * 16 + pj];
        if (i == j) v += ALPHA;
    } else if (bi == bj + 1) {
        v = Bv[b * 3840 + bj * 256 + pi * 16 + pj];
    } else if (bj == bi + 1) {
        v = Bv[b * 3840 + bi * 256 + pj * 16 + pi];
    }
    Pm[idx] = v;
}

// ============================================================================
// Banded Cholesky (unchanged)
// ============================================================================
__global__ __launch_bounds__(64) void chol_band(
    const float* __restrict__ Dv, const float* __restrict__ Bv,
    float* __restrict__ Lb_g)
{
    __shared__ float Lb[256 * 32];
    __shared__ float Ds[4096];
    __shared__ float Bs2[3840];
    const int b = blockIdx.x, lane = threadIdx.x;
    for (int i = lane; i < 8192; i += 64) Lb[i] = 0.f;
    for (int i = lane; i < 4096; i += 64) Ds[i] = Dv[b * 4096 + i];
    for (int i = lane; i < 3840; i += 64) Bs2[i] = Bv[b * 3840 + i];
    __syncthreads();

    const int d = lane;
    for (int j = 0; j < 256; j++) {
        const int i = j + d;
        float s = 0.f;
        if (d < 32 && i < 256) {
            int bi = i >> 4, bj = j >> 4, pi = i & 15, pj = j & 15;
            float a;
            if (bi == bj)           a = Ds[bi * 256 + pi * 16 + pj] + (i == j ? ALPHA : 0.f);
            else if (bi == bj + 1)  a = Bs2[bj * 256 + pi * 16 + pj];
            else                    a = 0.f;
            float s0 = 0.f, s1 = 0.f;
            int kmin = i - 31; if (kmin < 0) kmin = 0;
            int k = kmin;
            for (; k + 1 < j; k += 2) {
                s0 = fmaf(Lb[i * 32 + (i - k)],     Lb[j * 32 + (j - k)],     s0);
                s1 = fmaf(Lb[i * 32 + (i - k - 1)], Lb[j * 32 + (j - k - 1)], s1);
            }
            if (k < j) s0 = fmaf(Lb[i * 32 + (i - k)], Lb[j * 32 + (j - k)], s0);
            s = a - s0 - s1;
        }
        float diag = __shfl(s, 0);
        float Ljj = sqrtf(diag);
        if (d == 0)                  Lb[j * 32] = Ljj;
        else if (d < 32 && i < 256)  Lb[i * 32 + d] = s / Ljj;
        __syncthreads();
    }
    for (int i = lane; i < 8192; i += 64) Lb_g[b * 8192 + i] = Lb[i];
}

// ============================================================================
// cov = inv(L) (unchanged)
// ============================================================================
__global__ __launch_bounds__(256) void inv_band(
    const float* __restrict__ Lb_g, float* __restrict__ cov)
{
    __shared__ float win[32 * 256];
    const int b = blockIdx.x, j = threadIdx.x;
    const float* Lb = Lb_g + b * 8192;
    float* covb = cov + (size_t)b * 65536;
    for (int i = 0; i < 256; i++) {
        float Lr[32];
        #pragma unroll
        for (int d = 0; d < 32; d++) Lr[d] = Lb[i * 32 + d];
        float g = 0.f;
        if (i >= j) {
            float s = 0.f;
            #pragma unroll
            for (int d = 1; d < 32; d++) {
                int k = i - d;
                if (k >= j) s = fmaf(Lr[d], win[(k & 31) * 256 + j], s);
            }
            g = ((i == j) ? 1.f - s : -s) / Lr[0];
            win[(i & 31) * 256 + j] = g;
        }
        covb[i * 256 + j] = g;
    }
}

// ============================================================================
// z = mu + cov @ eps (unchanged)
// ============================================================================
__global__ __launch_bounds__(256) void zvec_k(
    const float* __restrict__ cov, const float* __restrict__ mu,
    const float* __restrict__ eps, float* __restrict__ z)
{
    __shared__ float es[256];
    const int b = blockIdx.x, i = threadIdx.x;
    es[i] = eps[b * 256 + i];
    __syncthreads();
    const float4* row = (const float4*)(cov + (size_t)b * 65536 + i * 256);
    float s = 0.f;
    #pragma unroll 8
    for (int k = 0; k < 64; k++) {
        float4 v = row[k];
        s = fmaf(v.x, es[4 * k], s);
        s = fmaf(v.y, es[4 * k + 1], s);
        s = fmaf(v.z, es[4 * k + 2], s);
        s = fmaf(v.w, es[4 * k + 3], s);
    }
    z[b * 256 + i] = mu[b * 256 + i] + s;
}

// ============================================================================
// Decoder FC (unchanged)
// ============================================================================
__global__ __launch_bounds__(256) void fc_dec_k(
    const float* __restrict__ z, const float* __restrict__ w,
    const float* __restrict__ bias, float* __restrict__ hd0)
{
    __shared__ float zs[256];
    const int blk = blockIdx.x;
    const int b = blk >> 2;
    const int f = ((blk & 3) << 8) + threadIdx.x;
    zs[threadIdx.x] = z[b * 256 + threadIdx.x];
    __syncthreads();
    const float4* wr = (const float4*)(w + f * 256);
    float s = 0.f;
    #pragma unroll 8
    for (int k = 0; k < 64; k++) {
        float4 v = wr[k];
        s = fmaf(v.x, zs[4 * k], s);
        s = fmaf(v.y, zs[4 * k + 1], s);
        s = fmaf(v.z, zs[4 * k + 2], s);
        s = fmaf(v.w, zs[4 * k + 3], s);
    }
    hd0[b * 1024 + f] = s + bias[f];
}

// ============================================================================
// Decoder weight transpose: [Cin][Cout][3][3] -> [wk][Cin][Cout]  (run once
// per launch into d_ws; makes co contiguous for coalesced/uniform loads).
// ============================================================================
__global__ __launch_bounds__(256) void transpose_all(
    const float* __restrict__ w5, const float* __restrict__ w4,
    const float* __restrict__ w3, const float* __restrict__ w2,
    float* __restrict__ t5, float* __restrict__ t4,
    float* __restrict__ t3, float* __restrict__ t2)
{
    int idx = blockIdx.x * 256 + threadIdx.x;   // total 101376
    if (idx >= 101376) return;
    const float* w; float* t; int CIN, COUT, loc;
    if (idx < 36864)      { w = w5; t = t5; CIN = 64; COUT = 64; loc = idx; }
    else if (idx < 73728) { w = w4; t = t4; CIN = 64; COUT = 64; loc = idx - 36864; }
    else if (idx < 92160) { w = w3; t = t3; CIN = 64; COUT = 32; loc = idx - 73728; }
    else                  { w = w2; t = t2; CIN = 32; COUT = 32; loc = idx - 92160; }
    int wk = loc % 9; int r = loc / 9; int co = r % COUT; int ci = r / COUT;
    t[wk * CIN * COUT + ci * COUT + co] = w[loc];
}

// ============================================================================
// Decoder v2: parity-class specialization.
// For stride-2/k3/p1/op1 convT: out[oy] += in[iy]*w[ky], ky = oy+1-2*iy.
//   oy even (PY=0): single tap ky=1, iy=ey.
//   oy odd  (PY=1): ky=2 (iy=ey) + ky=0 (iy=ey+1, guarded at top edge).
// Each parity class (PY,PX) is a compile-time template -> fully unrolled,
// wave-uniform branches, uniform/coalesced weight loads from [wk][ci][co].
// ============================================================================
__device__ __forceinline__ float eluf(float v) { return v > 0.f ? v : expf(v) - 1.f; }

template<int PY, int PX, int HIN, int WIN, class F>
__device__ __forceinline__ void for_taps(int ey, int ex, F&& f) {
    // f(wk, iy, ix, valid)
    if (PY == 0) {
        if (PX == 0) { f(4, ey, ex, true); }
        else         { f(5, ey, ex, true); f(3, ey, ex + 1, ex + 1 < WIN); }
    } else {
        if (PX == 0) { f(7, ey, ex, true); f(1, ey + 1, ex, ey + 1 < HIN); }
        else {
            f(8, ey, ex, true);
            f(6, ey, ex + 1, ex + 1 < WIN);
            f(2, ey + 1, ex, ey + 1 < HIN);
            f(0, ey + 1, ex + 1, (ey + 1 < HIN) && (ex + 1 < WIN));
        }
    }
}

// T4: 64ci 2x2 -> 64co 4x4.  lane=co, wave -> one class pixel (uniform).
template<int PY, int PX>
__device__ __forceinline__ void t4_class(
    const float* __restrict__ wt4t, const float* __restrict__ bt4,
    const float* __restrict__ d1, float* __restrict__ d2,
    int co, int ey, int ex)
{
    float acc = 0.f;
    for (int ci = 0; ci < 64; ci++) {
        const float* a = d1 + ci * 4;
        const float* w = wt4t + ci * 64 + co;
        for_taps<PY, PX, 2, 2>(ey, ex, [&](int wk, int iy, int ix, bool v) {
            float av = v ? a[iy * 2 + ix] : 0.f;
            acc = fmaf(av, w[wk * 4096], acc);
        });
    }
    const int oy = 2 * ey + PY, ox = 2 * ex + PX;
    d2[co * 16 + oy * 4 + ox] = eluf(acc + bt4[co]);
}

// T3: 64ci 4x4 -> 32co 8x8.  px = tid&15, cog = tid>>4 (2 co each).
template<int PY, int PX>
__device__ __forceinline__ void t3_class(
    const float* __restrict__ wt3t, const float* __restrict__ bt3,
    const float* __restrict__ d2, float* __restrict__ d3,
    int cog, int px)
{
    const int ey = px >> 2, ex = px & 3;
    float acc0 = 0.f, acc1 = 0.f;
    for (int ci = 0; ci < 64; ci++) {
        const float* a = d2 + ci * 16;
        const float2* w2p = (const float2*)(wt3t + ci * 32 + cog * 2);
        for_taps<PY, PX, 4, 4>(ey, ex, [&](int wk, int iy, int ix, bool v) {
            float av = v ? a[iy * 4 + ix] : 0.f;
            float2 wv = w2p[wk * 1024];   // wk*2048 floats
            acc0 = fmaf(av, wv.x, acc0);
            acc1 = fmaf(av, wv.y, acc1);
        });
    }
    const int oy = 2 * ey + PY, ox = 2 * ex + PX;
    const int co = cog * 2;
    d3[co * 72 + oy * 9 + ox]       = eluf(acc0 + bt3[co]);
    d3[(co + 1) * 72 + oy * 9 + ox] = eluf(acc1 + bt3[co + 1]);
}

// T2: 32ci 8x8 -> 32co 16x16.  lane = class pixel (64), wave = co octet.
template<int PY, int PX>
__device__ __forceinline__ void t2_class(
    const float* __restrict__ wt2t, const float* __restrict__ bt2,
    const float* __restrict__ d3, float* __restrict__ d4,
    int cogrp, int lane)
{
    const int ey = lane >> 3, ex = lane & 7;
    float acc[8] = {};
    for (int ci = 0; ci < 32; ci++) {
        const float* a = d3 + ci * 72;
        const float4* w4p = (const float4*)(wt2t + ci * 32 + cogrp * 8);
        for_taps<PY, PX, 8, 8>(ey, ex, [&](int wk, int iy, int ix, bool v) {
            float av = v ? a[iy * 9 + ix] : 0.f;
            float4 wa = w4p[wk * 256];       // wk*1024 floats
            float4 wb = w4p[wk * 256 + 1];
            acc[0] = fmaf(av, wa.x, acc[0]);
            acc[1] = fmaf(av, wa.y, acc[1]);
            acc[2] = fmaf(av, wa.z, acc[2]);
            acc[3] = fmaf(av, wa.w, acc[3]);
            acc[4] = fmaf(av, wb.x, acc[4]);
            acc[5] = fmaf(av, wb.y, acc[5]);
            acc[6] = fmaf(av, wb.z, acc[6]);
            acc[7] = fmaf(av, wb.w, acc[7]);
        });
    }
    const int oy = 2 * ey + PY, ox = 2 * ex + PX;
    #pragma unroll
    for (int r = 0; r < 8; r++)
        d4[(cogrp * 8 + r) * 256 + oy * 16 + ox] = eluf(acc[r] + bt2[cogrp * 8 + r]);
}

// T1: 32ci 16x16 -> 1co 32x32 + sigmoid.  thread = class pixel (256).
template<int PY, int PX>
__device__ __forceinline__ void t1_class(
    const float* __restrict__ wt1, float bb,
    const float* __restrict__ d4, float* __restrict__ xr_img,
    int ey, int ex)
{
    float acc = 0.f;
    for (int ci = 0; ci < 32; ci++) {
        const float* a = d4 + ci * 256;
        const float* w = wt1 + ci * 9;
        for_taps<PY, PX, 16, 16>(ey, ex, [&](int wk, int iy, int ix, bool v) {
            float av = v ? a[iy * 16 + ix] : 0.f;
            acc = fmaf(av, w[wk], acc);
        });
    }
    const int oy = 2 * ey + PY, ox = 2 * ex + PX;
    xr_img[oy * 32 + ox] = 1.f / (1.f + expf(-(acc + bb)));
}

__global__ __launch_bounds__(256) void dec_fused(
    const float* __restrict__ hd0,
    const float* __restrict__ wt5t, const float* __restrict__ bt5,
    const float* __restrict__ wt4t, const float* __restrict__ bt4,
    const float* __restrict__ wt3t, const float* __restrict__ bt3,
    const float* __restrict__ wt2t, const float* __restrict__ bt2,
    const float* __restrict__ wt1,  const float* __restrict__ bt1,
    float* __restrict__ xr)
{
    __shared__ float d0[64];
    __shared__ float d1[64 * 4];     // [co][2*2]
    __shared__ float d2[64 * 16];    // [co][4*4]
    __shared__ float d3[32 * 72];    // [co][8*9]  x padded to 9
    __shared__ float d4[32 * 256];   // [co][16*16]
    const int n = blockIdx.x, tid = threadIdx.x;
    const int lane = tid & 63;
    const int wv = __builtin_amdgcn_readfirstlane(tid >> 6);

    if (tid < 64) d0[tid] = hd0[n * 64 + tid];
    __syncthreads();

    // T5: 64x1x1 -> 64x2x2. lane=co, wave -> output pixel. Single tap.
    {
        const int co = lane;
        const int wk = ((wv >> 1) + 1) * 3 + ((wv & 1) + 1);
        const float* wp = wt5t + wk * 4096 + co;
        float s = bt5[co];
        for (int ci = 0; ci < 64; ci++)
            s = fmaf(d0[ci], wp[ci * 64], s);
        d1[co * 4 + wv] = eluf(s);
    }
    __syncthreads();

    // T4: lane=co, wave -> class pixel (ey,ex) = (wv>>1, wv&1)
    {
        const int co = lane, ey = wv >> 1, ex = wv & 1;
        t4_class<0, 0>(wt4t, bt4, d1, d2, co, ey, ex);
        t4_class<0, 1>(wt4t, bt4, d1, d2, co, ey, ex);
        t4_class<1, 0>(wt4t, bt4, d1, d2, co, ey, ex);
        t4_class<1, 1>(wt4t, bt4, d1, d2, co, ey, ex);
    }
    __syncthreads();

    // T3: px = tid&15, cog = tid>>4
    {
        const int px = tid & 15, cog = tid >> 4;
        t3_class<0, 0>(wt3t, bt3, d2, d3, cog, px);
        t3_class<0, 1>(wt3t, bt3, d2, d3, cog, px);
        t3_class<1, 0>(wt3t, bt3, d2, d3, cog, px);
        t3_class<1, 1>(wt3t, bt3, d2, d3, cog, px);
    }
    __syncthreads();

    // T2: lane = class pixel, wave = co octet
    {
        const int cogrp = wv;
        t2_class<0, 0>(wt2t, bt2, d3, d4, cogrp, lane);
        t2_class<0, 1>(wt2t, bt2, d3, d4, cogrp, lane);
        t2_class<1, 0>(wt2t, bt2, d3, d4, cogrp, lane);
        t2_class<1, 1>(wt2t, bt2, d3, d4, cogrp, lane);
    }
    __syncthreads();

    // T1: thread = class pixel
    {
        const int ey = tid >> 4, ex = tid & 15;
        const float bb = bt1[0];
        float* xi = xr + n * 1024;
        t1_class<0, 0>(wt1, bb, d4, xi, ey, ex);
        t1_class<0, 1>(wt1, bb, d4, xi, ey, ex);
        t1_class<1, 0>(wt1, bb, d4, xi, ey, ex);
        t1_class<1, 1>(wt1, bb, d4, xi, ey, ex);
    }
}

// ============================================================================
extern "C" void kernel_launch(void* const* d_in, const int* in_sizes, int n_in,
                              void* d_out, int out_size, void* d_ws, size_t ws_size,
                              hipStream_t stream)
{
    (void)in_sizes; (void)n_in; (void)out_size; (void)ws_size;
    const float* x    = (const float*)d_in[0];
    const float* eps  = (const float*)d_in[1];
    const float* w1 = (const float*)d_in[2];  const float* b1 = (const float*)d_in[3];
    const float* w2 = (const float*)d_in[4];  const float* b2 = (const float*)d_in[5];
    const float* w3 = (const float*)d_in[6];  const float* b3 = (const float*)d_in[7];
    const float* w4 = (const float*)d_in[8];  const float* b4 = (const float*)d_in[9];
    const float* w5 = (const float*)d_in[10]; const float* b5 = (const float*)d_in[11];
    const float* fc_mu_w = (const float*)d_in[12]; const float* fc_mu_b = (const float*)d_in[13];
    const float* fc_D_w  = (const float*)d_in[14]; const float* fc_D_b  = (const float*)d_in[15];
    const float* fc_B_w  = (const float*)d_in[16]; const float* fc_B_b  = (const float*)d_in[17];
    const float* fc_dec_w = (const float*)d_in[18]; const float* fc_dec_b = (const float*)d_in[19];
    const float* wt5 = (const float*)d_in[20]; const float* bt5 = (const float*)d_in[21];
    const float* wt4 = (const float*)d_in[22]; const float* bt4 = (const float*)d_in[23];
    const float* wt3 = (const float*)d_in[24]; const float* bt3 = (const float*)d_in[25];
    const float* wt2 = (const float*)d_in[26]; const float* bt2 = (const float*)d_in[27];
    const float* wt1 = (const float*)d_in[28]; const float* bt1 = (const float*)d_in[29];

    // workspace layout (floats): total 4,819,968 (~19.3 MB)
    float* ws   = (float*)d_ws;
    float* h    = ws;                  // 262144  [4096][64]
    float* Dv   = ws + 262144;         // 1048576 [256][4096]
    float* Bv   = ws + 1310720;        // 983040  [256][3840]
    float* Lb   = ws + 2293760;        // 2097152 [256][256][32]
    float* z    = ws + 4390912;        // 65536
    float* hd0  = ws + 4456448;        // 262144  [4096][64]
    float* wt5t = ws + 4718592;        // 36864   [9][64][64]
    float* wt4t = ws + 4755456;        // 36864   [9][64][64]
    float* wt3t = ws + 4792320;        // 18432   [9][64][32]
    float* wt2t = ws + 4810752;        // 9216    [9][32][32]

    // output layout: xr | mu | cov | Pm
    float* out = (float*)d_out;
    float* xr  = out;                 // 4194304
    float* mu  = out + 4194304;       // 65536
    float* cov = out + 4259840;       // 16777216
    float* Pm  = out + 21037056;      // 16777216

    transpose_all<<<396, 256, 0, stream>>>(wt5, wt4, wt3, wt2, wt5t, wt4t, wt3t, wt2t);
    enc_fused<<<4096, 256, 0, stream>>>(x, w1, b1, w2, b2, w3, b3, w4, b4, w5, b5, h);
    fc_enc<<<dim3(128, 4), 256, 0, stream>>>(h, fc_mu_w, fc_mu_b, fc_D_w, fc_D_b,
                                             fc_B_w, fc_B_b, mu, Dv, Bv);
    build_pm<<<65536, 256, 0, stream>>>(Dv, Bv, Pm);
    chol_band<<<256, 64, 0, stream>>>(Dv, Bv, Lb);
    inv_band<<<256, 256, 0, stream>>>(Lb, cov);
    zvec_k<<<256, 256, 0, stream>>>(cov, mu, eps, z);
    fc_dec_k<<<1024, 256, 0, stream>>>(z, fc_dec_w, fc_dec_b, hd0);
    dec_fused<<<4096, 256, 0, stream>>>(hd0, wt5t, bt5, wt4t, bt4, wt3t, bt3,
                                        wt2t, bt2, wt1, bt1, xr);
}

// Round 3
// 1939.224 us; speedup vs baseline: 1.7163x; 1.2119x over previous
//
#include <hip/hip_runtime.h>
#include <cmath>

#define ALPHA 0.5f

// ============================================================================
// Weight transpose: conv weights -> [k][ci][co] for coalesced/uniform access.
// Decoder (ConvT) src layout [Cin][Cout][3][3]; encoder (Conv) src [Cout][Cin][3][3].
// ============================================================================
__global__ __launch_bounds__(256) void transpose_all8(
    const float* __restrict__ dw5, const float* __restrict__ dw4,
    const float* __restrict__ dw3, const float* __restrict__ dw2,
    const float* __restrict__ ew2, const float* __restrict__ ew3,
    const float* __restrict__ ew4, const float* __restrict__ ew5,
    float* __restrict__ t5, float* __restrict__ t4,
    float* __restrict__ t3, float* __restrict__ t2,
    float* __restrict__ e2, float* __restrict__ e3,
    float* __restrict__ e4, float* __restrict__ e5)
{
    int idx = blockIdx.x * 256 + threadIdx.x;   // total 202752
    if (idx >= 202752) return;
    const float* w; float* t; int CIN, COUT, loc; bool enc = false;
    if (idx < 36864)       { w = dw5; t = t5; CIN = 64; COUT = 64; loc = idx; }
    else if (idx < 73728)  { w = dw4; t = t4; CIN = 64; COUT = 64; loc = idx - 36864; }
    else if (idx < 92160)  { w = dw3; t = t3; CIN = 64; COUT = 32; loc = idx - 73728; }
    else if (idx < 101376) { w = dw2; t = t2; CIN = 32; COUT = 32; loc = idx - 92160; }
    else if (idx < 110592) { w = ew2; t = e2; CIN = 32; COUT = 32; loc = idx - 101376; enc = true; }
    else if (idx < 129024) { w = ew3; t = e3; CIN = 32; COUT = 64; loc = idx - 110592; enc = true; }
    else if (idx < 165888) { w = ew4; t = e4; CIN = 64; COUT = 64; loc = idx - 129024; enc = true; }
    else                   { w = ew5; t = e5; CIN = 64; COUT = 64; loc = idx - 165888; enc = true; }
    int wk = loc % 9; int r = loc / 9; int ci, co;
    if (enc) { ci = r % CIN;  co = r / CIN;  }   // src [co][ci][k]
    else     { co = r % COUT; ci = r / COUT; }   // src [ci][co][k]
    t[wk * CIN * COUT + ci * COUT + co] = w[loc];
}

// ============================================================================
// Encoder v2: fused 5 convs, one block/image. Conflict-free LDS layouts:
//   a1: [ci][16 rows][pitch 18], x parity-split: col(x) = (x&1)? 9+(x>>1) : x>>1
//       -> conv2's stride-2 lane reads become stride-1, rows tile banks 2-way.
//   img: [32 rows][pitch 40], same parity split (col(x) odd -> 20+(x>>1)).
// Weights from [k][ci][co] transposes: conv2 via wave-uniform s_loads,
// conv3 float4, conv4/5 coalesced. conv4 parity-class templated (no guards).
// LDS total 51200 B (region B aliased over phases).
// ============================================================================
template<int OY, int OX>
__device__ __forceinline__ float c4_cls(
    const float* __restrict__ a3s, const float* __restrict__ w4t,
    float acc, int co)
{
    for (int ci = 0; ci < 64; ci++) {
        #pragma unroll
        for (int ky = 0; ky < 3; ky++) {
            const int iy = 2 * OY - 1 + ky;
            if (iy < 0) continue;
            #pragma unroll
            for (int kx = 0; kx < 3; kx++) {
                const int ix = 2 * OX - 1 + kx;
                if (ix < 0) continue;
                acc = fmaf(a3s[ci * 16 + iy * 4 + ix],
                           w4t[(ky * 3 + kx) * 4096 + ci * 64 + co], acc);
            }
        }
    }
    return acc;
}

__global__ __launch_bounds__(256) void enc_fused(
    const float* __restrict__ x,
    const float* __restrict__ w1,  const float* __restrict__ b1,
    const float* __restrict__ w2t, const float* __restrict__ b2,
    const float* __restrict__ w3t, const float* __restrict__ b3,
    const float* __restrict__ w4t, const float* __restrict__ b4,
    const float* __restrict__ w5t, const float* __restrict__ b5,
    float* __restrict__ hout)
{
    __shared__ __align__(16) float smem[12800];   // 51200 B
    float* a1s  = smem;          // [32][16][18] = 9216 fl (36864 B)
    float* bse  = smem + 9216;   // region B: 3584 fl, aliased by phase
    float* imgs = bse;           // phase0: [32][40] = 1280 fl
    float* a2s  = bse;           // phase1+: [32][64] = 2048 fl
    float* a3s  = bse + 2048;    // [64][16] = 1024 fl
    float* a4s  = bse + 3072;    // [64][4]  = 256 fl
    float* reds = bse + 3328;    // [4][64]  = 256 fl

    const int n = blockIdx.x;
    const int tid = threadIdx.x;

    // stage image, parity-split cols, pitch 40
    const float* xi = x + n * 1024;
    #pragma unroll
    for (int i = 0; i < 4; i++) {
        int idx = tid + 256 * i;
        int iy = idx >> 5, ix = idx & 31;
        int col = (ix & 1) ? 20 + (ix >> 1) : (ix >> 1);
        imgs[iy * 40 + col] = xi[idx];
    }
    __syncthreads();

    // conv1: 1->32, 32x32 -> 16x16. thread = out pixel.
    {
        const int oy = tid >> 4, ox = tid & 15;
        float patch[9];
        #pragma unroll
        for (int ky = 0; ky < 3; ky++) {
            const int iy = 2 * oy - 1 + ky;
            #pragma unroll
            for (int kx = 0; kx < 3; kx++) {
                const int ix = 2 * ox - 1 + kx;
                bool v = (iy >= 0) && (ix >= 0);
                int col = (ix & 1) ? 20 + (ix >> 1) : (ix >> 1);
                patch[ky * 3 + kx] = v ? imgs[iy * 40 + col] : 0.f;
            }
        }
        const int ocol = (ox & 1) ? 9 + (ox >> 1) : (ox >> 1);
        for (int c = 0; c < 32; c++) {
            float acc = b1[c];                       // uniform -> s_load
            #pragma unroll
            for (int k = 0; k < 9; k++) acc = fmaf(patch[k], w1[c * 9 + k], acc);
            a1s[c * 288 + oy * 18 + ocol] = fmaxf(acc, 0.f);
        }
    }
    __syncthreads();

    // conv2: 32->32, 16x16 -> 8x8. p = pixel, co = wave-uniform base + 8.
    {
        const int p = tid & 63, oy = p >> 3, ox = p & 7;
        const int c0u = __builtin_amdgcn_readfirstlane(tid >> 6);
        const int cobase = c0u * 8;
        float acc[8];
        #pragma unroll
        for (int r = 0; r < 8; r++) acc[r] = b2[cobase + r];   // uniform s_load
        for (int ci = 0; ci < 32; ci++) {
            float patch[9];
            #pragma unroll
            for (int ky = 0; ky < 3; ky++) {
                const int iy = 2 * oy - 1 + ky;
                #pragma unroll
                for (int kx = 0; kx < 3; kx++) {
                    const int ix = 2 * ox - 1 + kx;
                    bool v = (iy >= 0) && (ix >= 0);
                    int col = (ix & 1) ? 9 + (ix >> 1) : (ix >> 1);
                    patch[ky * 3 + kx] = v ? a1s[ci * 288 + iy * 18 + col] : 0.f;
                }
            }
            const float* wci = w2t + ci * 32 + cobase;   // [k][ci][32co]; uniform
            #pragma unroll
            for (int k = 0; k < 9; k++) {
                #pragma unroll
                for (int r = 0; r < 8; r++)
                    acc[r] = fmaf(patch[k], wci[k * 1024 + r], acc[r]);
            }
        }
        __syncthreads();   // a1 consumed; region B (img) about to be overwritten
        #pragma unroll
        for (int r = 0; r < 8; r++)
            a2s[(cobase + r) * 64 + p] = fmaxf(acc[r], 0.f);
    }
    __syncthreads();

    // conv3: 32->64, 8x8 -> 4x4. px = tid&15, cg = tid>>4, co = cg*4+r.
    {
        const int px = tid & 15, oy = px >> 2, ox = px & 3;
        const int cg = tid >> 4;
        float4 bv = ((const float4*)b3)[cg];
        float acc[4] = {bv.x, bv.y, bv.z, bv.w};
        for (int ci = 0; ci < 32; ci++) {
            float patch[9];
            #pragma unroll
            for (int ky = 0; ky < 3; ky++) {
                const int iy = 2 * oy - 1 + ky;
                #pragma unroll
                for (int kx = 0; kx < 3; kx++) {
                    const int ix = 2 * ox - 1 + kx;
                    bool v = (iy >= 0) && (ix >= 0);
                    patch[ky * 3 + kx] = v ? a2s[ci * 64 + iy * 8 + ix] : 0.f;
                }
            }
            #pragma unroll
            for (int k = 0; k < 9; k++) {
                float4 wv = *(const float4*)(w3t + k * 2048 + ci * 64 + cg * 4);
                acc[0] = fmaf(patch[k], wv.x, acc[0]);
                acc[1] = fmaf(patch[k], wv.y, acc[1]);
                acc[2] = fmaf(patch[k], wv.z, acc[2]);
                acc[3] = fmaf(patch[k], wv.w, acc[3]);
            }
        }
        #pragma unroll
        for (int r = 0; r < 4; r++)
            a3s[(cg * 4 + r) * 16 + px] = fmaxf(acc[r], 0.f);
    }
    __syncthreads();

    // conv4: 64->64, 4x4 -> 2x2. lane = co, wave = parity class (templated).
    {
        const int co = tid & 63;
        const int cls = __builtin_amdgcn_readfirstlane(tid >> 6);
        float acc = b4[co];
        if (cls == 0)      acc = c4_cls<0, 0>(a3s, w4t, acc, co);
        else if (cls == 1) acc = c4_cls<0, 1>(a3s, w4t, acc, co);
        else if (cls == 2) acc = c4_cls<1, 0>(a3s, w4t, acc, co);
        else               acc = c4_cls<1, 1>(a3s, w4t, acc, co);
        a4s[co * 4 + cls] = fmaxf(acc, 0.f);
    }
    __syncthreads();

    // conv5: 64->64, 2x2 -> 1x1. taps (ky,kx) in {1,2}^2 -> k = {4,5,7,8}.
    {
        const int c = tid & 63, part = tid >> 6;
        float s = 0.f;
        for (int ci = part * 16; ci < part * 16 + 16; ci++) {
            const float* av = a4s + ci * 4;
            s = fmaf(av[0], w5t[4 * 4096 + ci * 64 + c], s);
            s = fmaf(av[1], w5t[5 * 4096 + ci * 64 + c], s);
            s = fmaf(av[2], w5t[7 * 4096 + ci * 64 + c], s);
            s = fmaf(av[3], w5t[8 * 4096 + ci * 64 + c], s);
        }
        reds[part * 64 + c] = s;
    }
    __syncthreads();
    if (tid < 64) {
        float v = b5[tid] + reds[tid] + reds[64 + tid] + reds[128 + tid] + reds[192 + tid];
        hout[n * 64 + tid] = fmaxf(v, 0.f);
    }
}

// ============================================================================
// FC heads (unchanged)
// ============================================================================
__global__ __launch_bounds__(256) void fc_enc(
    const float* __restrict__ h,
    const float* __restrict__ wmu, const float* __restrict__ bmu,
    const float* __restrict__ wD,  const float* __restrict__ bD,
    const float* __restrict__ wB,  const float* __restrict__ bB,
    float* __restrict__ mu, float* __restrict__ Dv, float* __restrict__ Bv)
{
    __shared__ float As[32][65];
    __shared__ float Bs[32][65];
    const int tid = threadIdx.x;
    const int m0 = blockIdx.y * 64;
    const int n0 = blockIdx.x * 64;

    const float* wbase; const float* bias; float* outp; int stride; int nloc;
    if (n0 < 256)       { wbase = wmu; bias = bmu; outp = mu; stride = 256;  nloc = n0; }
    else if (n0 < 4352) { wbase = wD;  bias = bD;  outp = Dv; stride = 4096; nloc = n0 - 256; }
    else                { wbase = wB;  bias = bB;  outp = Bv; stride = 3840; nloc = n0 - 4352; }

    const int tx = tid & 15, ty = tid >> 4;
    float acc[4][4] = {};
    for (int k0 = 0; k0 < 1024; k0 += 32) {
        #pragma unroll
        for (int s = 0; s < 8; s++) {
            int l = tid + 256 * s;
            int row = l >> 5, kk = l & 31;
            As[kk][row] = h[(m0 + row) * 1024 + k0 + kk];
            Bs[kk][row] = wbase[(nloc + row) * 1024 + k0 + kk];
        }
        __syncthreads();
        #pragma unroll
        for (int kk = 0; kk < 32; kk++) {
            float av[4], bv[4];
            #pragma unroll
            for (int i = 0; i < 4; i++) av[i] = As[kk][ty * 4 + i];
            #pragma unroll
            for (int j = 0; j < 4; j++) bv[j] = Bs[kk][tx * 4 + j];
            #pragma unroll
            for (int i = 0; i < 4; i++)
                #pragma unroll
                for (int j = 0; j < 4; j++) acc[i][j] = fmaf(av[i], bv[j], acc[i][j]);
        }
        __syncthreads();
    }
    #pragma unroll
    for (int i = 0; i < 4; i++) {
        int m = m0 + ty * 4 + i;
        #pragma unroll
        for (int j = 0; j < 4; j++) {
            int nc = nloc + tx * 4 + j;
            outp[m * stride + nc] = acc[i][j] + bias[nc];
        }
    }
}

// ============================================================================
// Pm assembly (unchanged)
// ============================================================================
__global__ __launch_bounds__(256) void build_pm(
    const float* __restrict__ Dv, const float* __restrict__ Bv,
    float* __restrict__ Pm)
{
    const int idx = blockIdx.x * 256 + threadIdx.x;
    const int b = idx >> 16, rem = idx & 65535;
    const int i = rem >> 8, j = rem & 255;
    const int bi = i >> 4, pi = i & 15, bj = j >> 4, pj = j & 15;
    float v = 0.f;
    if (bi == bj) {
        v = Dv[b * 4096 + bi * 256 + pi * 16 + pj];
        if (i == j) v += ALPHA;
    } else if (bi == bj + 1) {
        v = Bv[b * 3840 + bj * 256 + pi * 16 + pj];
    } else if (bj == bi + 1) {
        v = Bv[b * 3840 + bi * 256 + pj * 16 + pi];
    }
    Pm[idx] = v;
}

// ============================================================================
// Banded Cholesky (unchanged)
// ============================================================================
__global__ __launch_bounds__(64) void chol_band(
    const float* __restrict__ Dv, const float* __restrict__ Bv,
    float* __restrict__ Lb_g)
{
    __shared__ float Lb[256 * 32];
    __shared__ float Ds[4096];
    __shared__ float Bs2[3840];
    const int b = blockIdx.x, lane = threadIdx.x;
    for (int i = lane; i < 8192; i += 64) Lb[i] = 0.f;
    for (int i = lane; i < 4096; i += 64) Ds[i] = Dv[b * 4096 + i];
    for (int i = lane; i < 3840; i += 64) Bs2[i] = Bv[b * 3840 + i];
    __syncthreads();

    const int d = lane;
    for (int j = 0; j < 256; j++) {
        const int i = j + d;
        float s = 0.f;
        if (d < 32 && i < 256) {
            int bi = i >> 4, bj = j >> 4, pi = i & 15, pj = j & 15;
            float a;
            if (bi == bj)           a = Ds[bi * 256 + pi * 16 + pj] + (i == j ? ALPHA : 0.f);
            else if (bi == bj + 1)  a = Bs2[bj * 256 + pi * 16 + pj];
            else                    a = 0.f;
            float s0 = 0.f, s1 = 0.f;
            int kmin = i - 31; if (kmin < 0) kmin = 0;
            int k = kmin;
            for (; k + 1 < j; k += 2) {
                s0 = fmaf(Lb[i * 32 + (i - k)],     Lb[j * 32 + (j - k)],     s0);
                s1 = fmaf(Lb[i * 32 + (i - k - 1)], Lb[j * 32 + (j - k - 1)], s1);
            }
            if (k < j) s0 = fmaf(Lb[i * 32 + (i - k)], Lb[j * 32 + (j - k)], s0);
            s = a - s0 - s1;
        }
        float diag = __shfl(s, 0);
        float Ljj = sqrtf(diag);
        if (d == 0)                  Lb[j * 32] = Ljj;
        else if (d < 32 && i < 256)  Lb[i * 32 + d] = s / Ljj;
        __syncthreads();
    }
    for (int i = lane; i < 8192; i += 64) Lb_g[b * 8192 + i] = Lb[i];
}

// ============================================================================
// cov = inv(L) (unchanged)
// ============================================================================
__global__ __launch_bounds__(256) void inv_band(
    const float* __restrict__ Lb_g, float* __restrict__ cov)
{
    __shared__ float win[32 * 256];
    const int b = blockIdx.x, j = threadIdx.x;
    const float* Lb = Lb_g + b * 8192;
    float* covb = cov + (size_t)b * 65536;
    for (int i = 0; i < 256; i++) {
        float Lr[32];
        #pragma unroll
        for (int d = 0; d < 32; d++) Lr[d] = Lb[i * 32 + d];
        float g = 0.f;
        if (i >= j) {
            float s = 0.f;
            #pragma unroll
            for (int d = 1; d < 32; d++) {
                int k = i - d;
                if (k >= j) s = fmaf(Lr[d], win[(k & 31) * 256 + j], s);
            }
            g = ((i == j) ? 1.f - s : -s) / Lr[0];
            win[(i & 31) * 256 + j] = g;
        }
        covb[i * 256 + j] = g;
    }
}

// ============================================================================
// z = mu + cov @ eps (unchanged)
// ============================================================================
__global__ __launch_bounds__(256) void zvec_k(
    const float* __restrict__ cov, const float* __restrict__ mu,
    const float* __restrict__ eps, float* __restrict__ z)
{
    __shared__ float es[256];
    const int b = blockIdx.x, i = threadIdx.x;
    es[i] = eps[b * 256 + i];
    __syncthreads();
    const float4* row = (const float4*)(cov + (size_t)b * 65536 + i * 256);
    float s = 0.f;
    #pragma unroll 8
    for (int k = 0; k < 64; k++) {
        float4 v = row[k];
        s = fmaf(v.x, es[4 * k], s);
        s = fmaf(v.y, es[4 * k + 1], s);
        s = fmaf(v.z, es[4 * k + 2], s);
        s = fmaf(v.w, es[4 * k + 3], s);
    }
    z[b * 256 + i] = mu[b * 256 + i] + s;
}

// ============================================================================
// Decoder FC (unchanged)
// ============================================================================
__global__ __launch_bounds__(256) void fc_dec_k(
    const float* __restrict__ z, const float* __restrict__ w,
    const float* __restrict__ bias, float* __restrict__ hd0)
{
    __shared__ float zs[256];
    const int blk = blockIdx.x;
    const int b = blk >> 2;
    const int f = ((blk & 3) << 8) + threadIdx.x;
    zs[threadIdx.x] = z[b * 256 + threadIdx.x];
    __syncthreads();
    const float4* wr = (const float4*)(w + f * 256);
    float s = 0.f;
    #pragma unroll 8
    for (int k = 0; k < 64; k++) {
        float4 v = wr[k];
        s = fmaf(v.x, zs[4 * k], s);
        s = fmaf(v.y, zs[4 * k + 1], s);
        s = fmaf(v.z, zs[4 * k + 2], s);
        s = fmaf(v.w, zs[4 * k + 3], s);
    }
    hd0[b * 1024 + f] = s + bias[f];
}

// ============================================================================
// Decoder (unchanged from R2 — parity-class templated)
// ============================================================================
__device__ __forceinline__ float eluf(float v) { return v > 0.f ? v : expf(v) - 1.f; }

template<int PY, int PX, int HIN, int WIN, class F>
__device__ __forceinline__ void for_taps(int ey, int ex, F&& f) {
    if (PY == 0) {
        if (PX == 0) { f(4, ey, ex, true); }
        else         { f(5, ey, ex, true); f(3, ey, ex + 1, ex + 1 < WIN); }
    } else {
        if (PX == 0) { f(7, ey, ex, true); f(1, ey + 1, ex, ey + 1 < HIN); }
        else {
            f(8, ey, ex, true);
            f(6, ey, ex + 1, ex + 1 < WIN);
            f(2, ey + 1, ex, ey + 1 < HIN);
            f(0, ey + 1, ex + 1, (ey + 1 < HIN) && (ex + 1 < WIN));
        }
    }
}

template<int PY, int PX>
__device__ __forceinline__ void t4_class(
    const float* __restrict__ wt4t, const float* __restrict__ bt4,
    const float* __restrict__ d1, float* __restrict__ d2,
    int co, int ey, int ex)
{
    float acc = 0.f;
    for (int ci = 0; ci < 64; ci++) {
        const float* a = d1 + ci * 4;
        const float* w = wt4t + ci * 64 + co;
        for_taps<PY, PX, 2, 2>(ey, ex, [&](int wk, int iy, int ix, bool v) {
            float av = v ? a[iy * 2 + ix] : 0.f;
            acc = fmaf(av, w[wk * 4096], acc);
        });
    }
    const int oy = 2 * ey + PY, ox = 2 * ex + PX;
    d2[co * 16 + oy * 4 + ox] = eluf(acc + bt4[co]);
}

template<int PY, int PX>
__device__ __forceinline__ void t3_class(
    const float* __restrict__ wt3t, const float* __restrict__ bt3,
    const float* __restrict__ d2, float* __restrict__ d3,
    int cog, int px)
{
    const int ey = px >> 2, ex = px & 3;
    float acc0 = 0.f, acc1 = 0.f;
    for (int ci = 0; ci < 64; ci++) {
        const float* a = d2 + ci * 16;
        const float2* w2p = (const float2*)(wt3t + ci * 32 + cog * 2);
        for_taps<PY, PX, 4, 4>(ey, ex, [&](int wk, int iy, int ix, bool v) {
            float av = v ? a[iy * 4 + ix] : 0.f;
            float2 wv = w2p[wk * 1024];
            acc0 = fmaf(av, wv.x, acc0);
            acc1 = fmaf(av, wv.y, acc1);
        });
    }
    const int oy = 2 * ey + PY, ox = 2 * ex + PX;
    const int co = cog * 2;
    d3[co * 72 + oy * 9 + ox]       = eluf(acc0 + bt3[co]);
    d3[(co + 1) * 72 + oy * 9 + ox] = eluf(acc1 + bt3[co + 1]);
}

template<int PY, int PX>
__device__ __forceinline__ void t2_class(
    const float* __restrict__ wt2t, const float* __restrict__ bt2,
    const float* __restrict__ d3, float* __restrict__ d4,
    int cogrp, int lane)
{
    const int ey = lane >> 3, ex = lane & 7;
    float acc[8] = {};
    for (int ci = 0; ci < 32; ci++) {
        const float* a = d3 + ci * 72;
        const float4* w4p = (const float4*)(wt2t + ci * 32 + cogrp * 8);
        for_taps<PY, PX, 8, 8>(ey, ex, [&](int wk, int iy, int ix, bool v) {
            float av = v ? a[iy * 9 + ix] : 0.f;
            float4 wa = w4p[wk * 256];
            float4 wb = w4p[wk * 256 + 1];
            acc[0] = fmaf(av, wa.x, acc[0]);
            acc[1] = fmaf(av, wa.y, acc[1]);
            acc[2] = fmaf(av, wa.z, acc[2]);
            acc[3] = fmaf(av, wa.w, acc[3]);
            acc[4] = fmaf(av, wb.x, acc[4]);
            acc[5] = fmaf(av, wb.y, acc[5]);
            acc[6] = fmaf(av, wb.z, acc[6]);
            acc[7] = fmaf(av, wb.w, acc[7]);
        });
    }
    const int oy = 2 * ey + PY, ox = 2 * ex + PX;
    #pragma unroll
    for (int r = 0; r < 8; r++)
        d4[(cogrp * 8 + r) * 256 + oy * 16 + ox] = eluf(acc[r] + bt2[cogrp * 8 + r]);
}

template<int PY, int PX>
__device__ __forceinline__ void t1_class(
    const float* __restrict__ wt1, float bb,
    const float* __restrict__ d4, float* __restrict__ xr_img,
    int ey, int ex)
{
    float acc = 0.f;
    for (int ci = 0; ci < 32; ci++) {
        const float* a = d4 + ci * 256;
        const float* w = wt1 + ci * 9;
        for_taps<PY, PX, 16, 16>(ey, ex, [&](int wk, int iy, int ix, bool v) {
            float av = v ? a[iy * 16 + ix] : 0.f;
            acc = fmaf(av, w[wk], acc);
        });
    }
    const int oy = 2 * ey + PY, ox = 2 * ex + PX;
    xr_img[oy * 32 + ox] = 1.f / (1.f + expf(-(acc + bb)));
}

__global__ __launch_bounds__(256) void dec_fused(
    const float* __restrict__ hd0,
    const float* __restrict__ wt5t, const float* __restrict__ bt5,
    const float* __restrict__ wt4t, const float* __restrict__ bt4,
    const float* __restrict__ wt3t, const float* __restrict__ bt3,
    const float* __restrict__ wt2t, const float* __restrict__ bt2,
    const float* __restrict__ wt1,  const float* __restrict__ bt1,
    float* __restrict__ xr)
{
    __shared__ float d0[64];
    __shared__ float d1[64 * 4];
    __shared__ float d2[64 * 16];
    __shared__ float d3[32 * 72];
    __shared__ float d4[32 * 256];
    const int n = blockIdx.x, tid = threadIdx.x;
    const int lane = tid & 63;
    const int wv = __builtin_amdgcn_readfirstlane(tid >> 6);

    if (tid < 64) d0[tid] = hd0[n * 64 + tid];
    __syncthreads();

    {
        const int co = lane;
        const int wk = ((wv >> 1) + 1) * 3 + ((wv & 1) + 1);
        const float* wp = wt5t + wk * 4096 + co;
        float s = bt5[co];
        for (int ci = 0; ci < 64; ci++)
            s = fmaf(d0[ci], wp[ci * 64], s);
        d1[co * 4 + wv] = eluf(s);
    }
    __syncthreads();

    {
        const int co = lane, ey = wv >> 1, ex = wv & 1;
        t4_class<0, 0>(wt4t, bt4, d1, d2, co, ey, ex);
        t4_class<0, 1>(wt4t, bt4, d1, d2, co, ey, ex);
        t4_class<1, 0>(wt4t, bt4, d1, d2, co, ey, ex);
        t4_class<1, 1>(wt4t, bt4, d1, d2, co, ey, ex);
    }
    __syncthreads();

    {
        const int px = tid & 15, cog = tid >> 4;
        t3_class<0, 0>(wt3t, bt3, d2, d3, cog, px);
        t3_class<0, 1>(wt3t, bt3, d2, d3, cog, px);
        t3_class<1, 0>(wt3t, bt3, d2, d3, cog, px);
        t3_class<1, 1>(wt3t, bt3, d2, d3, cog, px);
    }
    __syncthreads();

    {
        const int cogrp = wv;
        t2_class<0, 0>(wt2t, bt2, d3, d4, cogrp, lane);
        t2_class<0, 1>(wt2t, bt2, d3, d4, cogrp, lane);
        t2_class<1, 0>(wt2t, bt2, d3, d4, cogrp, lane);
        t2_class<1, 1>(wt2t, bt2, d3, d4, cogrp, lane);
    }
    __syncthreads();

    {
        const int ey = tid >> 4, ex = tid & 15;
        const float bb = bt1[0];
        float* xi = xr + n * 1024;
        t1_class<0, 0>(wt1, bb, d4, xi, ey, ex);
        t1_class<0, 1>(wt1, bb, d4, xi, ey, ex);
        t1_class<1, 0>(wt1, bb, d4, xi, ey, ex);
        t1_class<1, 1>(wt1, bb, d4, xi, ey, ex);
    }
}

// ============================================================================
extern "C" void kernel_launch(void* const* d_in, const int* in_sizes, int n_in,
                              void* d_out, int out_size, void* d_ws, size_t ws_size,
                              hipStream_t stream)
{
    (void)in_sizes; (void)n_in; (void)out_size; (void)ws_size;
    const float* x    = (const float*)d_in[0];
    const float* eps  = (const float*)d_in[1];
    const float* w1 = (const float*)d_in[2];  const float* b1 = (const float*)d_in[3];
    const float* w2 = (const float*)d_in[4];  const float* b2 = (const float*)d_in[5];
    const float* w3 = (const float*)d_in[6];  const float* b3 = (const float*)d_in[7];
    const float* w4 = (const float*)d_in[8];  const float* b4 = (const float*)d_in[9];
    const float* w5 = (const float*)d_in[10]; const float* b5 = (const float*)d_in[11];
    const float* fc_mu_w = (const float*)d_in[12]; const float* fc_mu_b = (const float*)d_in[13];
    const float* fc_D_w  = (const float*)d_in[14]; const float* fc_D_b  = (const float*)d_in[15];
    const float* fc_B_w  = (const float*)d_in[16]; const float* fc_B_b  = (const float*)d_in[17];
    const float* fc_dec_w = (const float*)d_in[18]; const float* fc_dec_b = (const float*)d_in[19];
    const float* wt5 = (const float*)d_in[20]; const float* bt5 = (const float*)d_in[21];
    const float* wt4 = (const float*)d_in[22]; const float* bt4 = (const float*)d_in[23];
    const float* wt3 = (const float*)d_in[24]; const float* bt3 = (const float*)d_in[25];
    const float* wt2 = (const float*)d_in[26]; const float* bt2 = (const float*)d_in[27];
    const float* wt1 = (const float*)d_in[28]; const float* bt1 = (const float*)d_in[29];

    // workspace layout (floats): total 4,921,344 (~19.7 MB)
    float* ws   = (float*)d_ws;
    float* h    = ws;                  // 262144  [4096][64]
    float* Dv   = ws + 262144;         // 1048576 [256][4096]
    float* Bv   = ws + 1310720;        // 983040  [256][3840]
    float* Lb   = ws + 2293760;        // 2097152 [256][256][32]
    float* z    = ws + 4390912;        // 65536
    float* hd0  = ws + 4456448;        // 262144  [4096][64]
    float* wt5t = ws + 4718592;        // 36864   [9][64][64]
    float* wt4t = ws + 4755456;        // 36864   [9][64][64]
    float* wt3t = ws + 4792320;        // 18432   [9][64][32]
    float* wt2t = ws + 4810752;        // 9216    [9][32][32]
    float* w2t  = ws + 4819968;        // 9216    [9][32][32]
    float* w3t  = ws + 4829184;        // 18432   [9][32][64]
    float* w4t  = ws + 4847616;        // 36864   [9][64][64]
    float* w5t  = ws + 4884480;        // 36864   [9][64][64]

    // output layout: xr | mu | cov | Pm
    float* out = (float*)d_out;
    float* xr  = out;                 // 4194304
    float* mu  = out + 4194304;       // 65536
    float* cov = out + 4259840;       // 16777216
    float* Pm  = out + 21037056;      // 16777216

    transpose_all8<<<792, 256, 0, stream>>>(wt5, wt4, wt3, wt2, w2, w3, w4, w5,
                                            wt5t, wt4t, wt3t, wt2t, w2t, w3t, w4t, w5t);
    enc_fused<<<4096, 256, 0, stream>>>(x, w1, b1, w2t, b2, w3t, b3, w4t, b4, w5t, b5, h);
    fc_enc<<<dim3(128, 4), 256, 0, stream>>>(h, fc_mu_w, fc_mu_b, fc_D_w, fc_D_b,
                                             fc_B_w, fc_B_b, mu, Dv, Bv);
    build_pm<<<65536, 256, 0, stream>>>(Dv, Bv, Pm);
    chol_band<<<256, 64, 0, stream>>>(Dv, Bv, Lb);
    inv_band<<<256, 256, 0, stream>>>(Lb, cov);
    zvec_k<<<256, 256, 0, stream>>>(cov, mu, eps, z);
    fc_dec_k<<<1024, 256, 0, stream>>>(z, fc_dec_w, fc_dec_b, hd0);
    dec_fused<<<4096, 256, 0, stream>>>(hd0, wt5t, bt5, wt4t, bt4, wt3t, bt3,
                                        wt2t, bt2, wt1, bt1, xr);
}

// Round 5
// 1636.449 us; speedup vs baseline: 2.0338x; 1.1850x over previous
//
#include <hip/hip_runtime.h>
#include <cmath>

#define ALPHA 0.5f

// ============================================================================
// Weight transpose: conv weights -> [k][ci][co] for coalesced/uniform access.
// Decoder (ConvT) src layout [Cin][Cout][3][3]; encoder (Conv) src [Cout][Cin][3][3].
// ============================================================================
__global__ __launch_bounds__(256) void transpose_all8(
    const float* __restrict__ dw5, const float* __restrict__ dw4,
    const float* __restrict__ dw3, const float* __restrict__ dw2,
    const float* __restrict__ ew2, const float* __restrict__ ew3,
    const float* __restrict__ ew4, const float* __restrict__ ew5,
    float* __restrict__ t5, float* __restrict__ t4,
    float* __restrict__ t3, float* __restrict__ t2,
    float* __restrict__ e2, float* __restrict__ e3,
    float* __restrict__ e4, float* __restrict__ e5)
{
    int idx = blockIdx.x * 256 + threadIdx.x;   // total 202752
    if (idx >= 202752) return;
    const float* w; float* t; int CIN, COUT, loc; bool enc = false;
    if (idx < 36864)       { w = dw5; t = t5; CIN = 64; COUT = 64; loc = idx; }
    else if (idx < 73728)  { w = dw4; t = t4; CIN = 64; COUT = 64; loc = idx - 36864; }
    else if (idx < 92160)  { w = dw3; t = t3; CIN = 64; COUT = 32; loc = idx - 73728; }
    else if (idx < 101376) { w = dw2; t = t2; CIN = 32; COUT = 32; loc = idx - 92160; }
    else if (idx < 110592) { w = ew2; t = e2; CIN = 32; COUT = 32; loc = idx - 101376; enc = true; }
    else if (idx < 129024) { w = ew3; t = e3; CIN = 32; COUT = 64; loc = idx - 110592; enc = true; }
    else if (idx < 165888) { w = ew4; t = e4; CIN = 64; COUT = 64; loc = idx - 129024; enc = true; }
    else                   { w = ew5; t = e5; CIN = 64; COUT = 64; loc = idx - 165888; enc = true; }
    int wk = loc % 9; int r = loc / 9; int ci, co;
    if (enc) { ci = r % CIN;  co = r / CIN;  }   // src [co][ci][k]
    else     { co = r % COUT; ci = r / COUT; }   // src [ci][co][k]
    t[wk * CIN * COUT + ci * COUT + co] = w[loc];
}

// ============================================================================
// Encoder (unchanged from R3)
// ============================================================================
template<int OY, int OX>
__device__ __forceinline__ float c4_cls(
    const float* __restrict__ a3s, const float* __restrict__ w4t,
    float acc, int co)
{
    for (int ci = 0; ci < 64; ci++) {
        #pragma unroll
        for (int ky = 0; ky < 3; ky++) {
            const int iy = 2 * OY - 1 + ky;
            if (iy < 0) continue;
            #pragma unroll
            for (int kx = 0; kx < 3; kx++) {
                const int ix = 2 * OX - 1 + kx;
                if (ix < 0) continue;
                acc = fmaf(a3s[ci * 16 + iy * 4 + ix],
                           w4t[(ky * 3 + kx) * 4096 + ci * 64 + co], acc);
            }
        }
    }
    return acc;
}

__global__ __launch_bounds__(256) void enc_fused(
    const float* __restrict__ x,
    const float* __restrict__ w1,  const float* __restrict__ b1,
    const float* __restrict__ w2t, const float* __restrict__ b2,
    const float* __restrict__ w3t, const float* __restrict__ b3,
    const float* __restrict__ w4t, const float* __restrict__ b4,
    const float* __restrict__ w5t, const float* __restrict__ b5,
    float* __restrict__ hout)
{
    __shared__ __align__(16) float smem[12800];   // 51200 B
    float* a1s  = smem;          // [32][16][18] = 9216 fl
    float* bse  = smem + 9216;   // region B: aliased by phase
    float* imgs = bse;           // phase0: [32][40]
    float* a2s  = bse;           // phase1+: [32][64]
    float* a3s  = bse + 2048;    // [64][16]
    float* a4s  = bse + 3072;    // [64][4]
    float* reds = bse + 3328;    // [4][64]

    const int n = blockIdx.x;
    const int tid = threadIdx.x;

    const float* xi = x + n * 1024;
    #pragma unroll
    for (int i = 0; i < 4; i++) {
        int idx = tid + 256 * i;
        int iy = idx >> 5, ix = idx & 31;
        int col = (ix & 1) ? 20 + (ix >> 1) : (ix >> 1);
        imgs[iy * 40 + col] = xi[idx];
    }
    __syncthreads();

    // conv1
    {
        const int oy = tid >> 4, ox = tid & 15;
        float patch[9];
        #pragma unroll
        for (int ky = 0; ky < 3; ky++) {
            const int iy = 2 * oy - 1 + ky;
            #pragma unroll
            for (int kx = 0; kx < 3; kx++) {
                const int ix = 2 * ox - 1 + kx;
                bool v = (iy >= 0) && (ix >= 0);
                int col = (ix & 1) ? 20 + (ix >> 1) : (ix >> 1);
                patch[ky * 3 + kx] = v ? imgs[iy * 40 + col] : 0.f;
            }
        }
        const int ocol = (ox & 1) ? 9 + (ox >> 1) : (ox >> 1);
        for (int c = 0; c < 32; c++) {
            float acc = b1[c];
            #pragma unroll
            for (int k = 0; k < 9; k++) acc = fmaf(patch[k], w1[c * 9 + k], acc);
            a1s[c * 288 + oy * 18 + ocol] = fmaxf(acc, 0.f);
        }
    }
    __syncthreads();

    // conv2
    {
        const int p = tid & 63, oy = p >> 3, ox = p & 7;
        const int c0u = __builtin_amdgcn_readfirstlane(tid >> 6);
        const int cobase = c0u * 8;
        float acc[8];
        #pragma unroll
        for (int r = 0; r < 8; r++) acc[r] = b2[cobase + r];
        for (int ci = 0; ci < 32; ci++) {
            float patch[9];
            #pragma unroll
            for (int ky = 0; ky < 3; ky++) {
                const int iy = 2 * oy - 1 + ky;
                #pragma unroll
                for (int kx = 0; kx < 3; kx++) {
                    const int ix = 2 * ox - 1 + kx;
                    bool v = (iy >= 0) && (ix >= 0);
                    int col = (ix & 1) ? 9 + (ix >> 1) : (ix >> 1);
                    patch[ky * 3 + kx] = v ? a1s[ci * 288 + iy * 18 + col] : 0.f;
                }
            }
            const float* wci = w2t + ci * 32 + cobase;
            #pragma unroll
            for (int k = 0; k < 9; k++) {
                #pragma unroll
                for (int r = 0; r < 8; r++)
                    acc[r] = fmaf(patch[k], wci[k * 1024 + r], acc[r]);
            }
        }
        __syncthreads();
        #pragma unroll
        for (int r = 0; r < 8; r++)
            a2s[(cobase + r) * 64 + p] = fmaxf(acc[r], 0.f);
    }
    __syncthreads();

    // conv3
    {
        const int px = tid & 15, oy = px >> 2, ox = px & 3;
        const int cg = tid >> 4;
        float4 bv = ((const float4*)b3)[cg];
        float acc[4] = {bv.x, bv.y, bv.z, bv.w};
        for (int ci = 0; ci < 32; ci++) {
            float patch[9];
            #pragma unroll
            for (int ky = 0; ky < 3; ky++) {
                const int iy = 2 * oy - 1 + ky;
                #pragma unroll
                for (int kx = 0; kx < 3; kx++) {
                    const int ix = 2 * ox - 1 + kx;
                    bool v = (iy >= 0) && (ix >= 0);
                    patch[ky * 3 + kx] = v ? a2s[ci * 64 + iy * 8 + ix] : 0.f;
                }
            }
            #pragma unroll
            for (int k = 0; k < 9; k++) {
                float4 wv = *(const float4*)(w3t + k * 2048 + ci * 64 + cg * 4);
                acc[0] = fmaf(patch[k], wv.x, acc[0]);
                acc[1] = fmaf(patch[k], wv.y, acc[1]);
                acc[2] = fmaf(patch[k], wv.z, acc[2]);
                acc[3] = fmaf(patch[k], wv.w, acc[3]);
            }
        }
        #pragma unroll
        for (int r = 0; r < 4; r++)
            a3s[(cg * 4 + r) * 16 + px] = fmaxf(acc[r], 0.f);
    }
    __syncthreads();

    // conv4
    {
        const int co = tid & 63;
        const int cls = __builtin_amdgcn_readfirstlane(tid >> 6);
        float acc = b4[co];
        if (cls == 0)      acc = c4_cls<0, 0>(a3s, w4t, acc, co);
        else if (cls == 1) acc = c4_cls<0, 1>(a3s, w4t, acc, co);
        else if (cls == 2) acc = c4_cls<1, 0>(a3s, w4t, acc, co);
        else               acc = c4_cls<1, 1>(a3s, w4t, acc, co);
        a4s[co * 4 + cls] = fmaxf(acc, 0.f);
    }
    __syncthreads();

    // conv5
    {
        const int c = tid & 63, part = tid >> 6;
        float s = 0.f;
        for (int ci = part * 16; ci < part * 16 + 16; ci++) {
            const float* av = a4s + ci * 4;
            s = fmaf(av[0], w5t[4 * 4096 + ci * 64 + c], s);
            s = fmaf(av[1], w5t[5 * 4096 + ci * 64 + c], s);
            s = fmaf(av[2], w5t[7 * 4096 + ci * 64 + c], s);
            s = fmaf(av[3], w5t[8 * 4096 + ci * 64 + c], s);
        }
        reds[part * 64 + c] = s;
    }
    __syncthreads();
    if (tid < 64) {
        float v = b5[tid] + reds[tid] + reds[64 + tid] + reds[128 + tid] + reds[192 + tid];
        hout[n * 64 + tid] = fmaxf(v, 0.f);
    }
}

// ============================================================================
// Pm zero-fill (Pm region of d_out is poisoned; band is overwritten by fc_enc)
// ============================================================================
__global__ __launch_bounds__(256) void pm_zero(float4* __restrict__ Pm4)
{
    Pm4[blockIdx.x * 256 + threadIdx.x] = make_float4(0.f, 0.f, 0.f, 0.f);
}

// ============================================================================
// FC heads: mu written to d_out; D/B heads written DIRECTLY into Pm (d_out)
// as block-tridiagonal entries (+ALPHA on diag, transposed super-diagonal).
// ============================================================================
__global__ __launch_bounds__(256) void fc_enc(
    const float* __restrict__ h,
    const float* __restrict__ wmu, const float* __restrict__ bmu,
    const float* __restrict__ wD,  const float* __restrict__ bD,
    const float* __restrict__ wB,  const float* __restrict__ bB,
    float* __restrict__ mu, float* __restrict__ Pm)
{
    __shared__ float As[32][65];
    __shared__ float Bs[32][65];
    const int tid = threadIdx.x;
    const int m0 = blockIdx.y * 64;
    const int n0 = blockIdx.x * 64;

    const float* wbase; const float* bias; int nloc; int region;
    if (n0 < 256)       { wbase = wmu; bias = bmu; nloc = n0;        region = 0; }
    else if (n0 < 4352) { wbase = wD;  bias = bD;  nloc = n0 - 256;  region = 1; }
    else                { wbase = wB;  bias = bB;  nloc = n0 - 4352; region = 2; }

    const int tx = tid & 15, ty = tid >> 4;
    float acc[4][4] = {};
    for (int k0 = 0; k0 < 1024; k0 += 32) {
        #pragma unroll
        for (int s = 0; s < 8; s++) {
            int l = tid + 256 * s;
            int row = l >> 5, kk = l & 31;
            As[kk][row] = h[(m0 + row) * 1024 + k0 + kk];
            Bs[kk][row] = wbase[(nloc + row) * 1024 + k0 + kk];
        }
        __syncthreads();
        #pragma unroll
        for (int kk = 0; kk < 32; kk++) {
            float av[4], bv[4];
            #pragma unroll
            for (int i = 0; i < 4; i++) av[i] = As[kk][ty * 4 + i];
            #pragma unroll
            for (int j = 0; j < 4; j++) bv[j] = Bs[kk][tx * 4 + j];
            #pragma unroll
            for (int i = 0; i < 4; i++)
                #pragma unroll
                for (int j = 0; j < 4; j++) acc[i][j] = fmaf(av[i], bv[j], acc[i][j]);
        }
        __syncthreads();
    }
    #pragma unroll
    for (int i = 0; i < 4; i++) {
        int m = m0 + ty * 4 + i;
        size_t pbase = (size_t)m * 65536;
        #pragma unroll
        for (int j = 0; j < 4; j++) {
            int nc = nloc + tx * 4 + j;
            float v = acc[i][j] + bias[nc];
            if (region == 0) {
                mu[m * 256 + nc] = v;
            } else {
                int t = nc >> 8, pi = (nc >> 4) & 15, pj = nc & 15;
                if (region == 1) {
                    int row = t * 16 + pi, col = t * 16 + pj;
                    Pm[pbase + row * 256 + col] = v + (pi == pj ? ALPHA : 0.f);
                } else {
                    int row = (t + 1) * 16 + pi, col = t * 16 + pj;
                    Pm[pbase + row * 256 + col] = v;      // sub-diagonal
                    Pm[pbase + col * 256 + row] = v;      // super-diagonal (transposed)
                }
            }
        }
    }
}

// ============================================================================
// Banded Cholesky; band loaded from Pm (ALPHA already included on diagonal).
// ============================================================================
__global__ __launch_bounds__(64) void chol_band(
    const float* __restrict__ Pm, float* __restrict__ Lb_g)
{
    __shared__ float Lb[256 * 32];
    __shared__ float Ds[4096];
    __shared__ float Bs2[3840];
    const int b = blockIdx.x, lane = threadIdx.x;
    const float* Pb = Pm + (size_t)b * 65536;
    for (int i = lane; i < 8192; i += 64) Lb[i] = 0.f;
    for (int i = lane; i < 4096; i += 64) {
        int t = i >> 8, r = (i >> 4) & 15, c = i & 15;
        Ds[i] = Pb[(t * 16 + r) * 256 + t * 16 + c];
    }
    for (int i = lane; i < 3840; i += 64) {
        int t = i >> 8, r = (i >> 4) & 15, c = i & 15;
        Bs2[i] = Pb[((t + 1) * 16 + r) * 256 + t * 16 + c];
    }
    __syncthreads();

    const int d = lane;
    for (int j = 0; j < 256; j++) {
        const int i = j + d;
        float s = 0.f;
        if (d < 32 && i < 256) {
            int bi = i >> 4, bj = j >> 4, pi = i & 15, pj = j & 15;
            float a;
            if (bi == bj)           a = Ds[bi * 256 + pi * 16 + pj];
            else if (bi == bj + 1)  a = Bs2[bj * 256 + pi * 16 + pj];
            else                    a = 0.f;
            float s0 = 0.f, s1 = 0.f;
            int kmin = i - 31; if (kmin < 0) kmin = 0;
            int k = kmin;
            for (; k + 1 < j; k += 2) {
                s0 = fmaf(Lb[i * 32 + (i - k)],     Lb[j * 32 + (j - k)],     s0);
                s1 = fmaf(Lb[i * 32 + (i - k - 1)], Lb[j * 32 + (j - k - 1)], s1);
            }
            if (k < j) s0 = fmaf(Lb[i * 32 + (i - k)], Lb[j * 32 + (j - k)], s0);
            s = a - s0 - s1;
        }
        float diag = __shfl(s, 0);
        float Ljj = sqrtf(diag);
        if (d == 0)                  Lb[j * 32] = Ljj;
        else if (d < 32 && i < 256)  Lb[i * 32 + d] = s / Ljj;
        __syncthreads();
    }
    for (int i = lane; i < 8192; i += 64) Lb_g[b * 8192 + i] = Lb[i];
}

// ============================================================================
// cov = inv(L) (unchanged)
// ============================================================================
__global__ __launch_bounds__(256) void inv_band(
    const float* __restrict__ Lb_g, float* __restrict__ cov)
{
    __shared__ float win[32 * 256];
    const int b = blockIdx.x, j = threadIdx.x;
    const float* Lb = Lb_g + b * 8192;
    float* covb = cov + (size_t)b * 65536;
    for (int i = 0; i < 256; i++) {
        float Lr[32];
        #pragma unroll
        for (int d = 0; d < 32; d++) Lr[d] = Lb[i * 32 + d];
        float g = 0.f;
        if (i >= j) {
            float s = 0.f;
            #pragma unroll
            for (int d = 1; d < 32; d++) {
                int k = i - d;
                if (k >= j) s = fmaf(Lr[d], win[(k & 31) * 256 + j], s);
            }
            g = ((i == j) ? 1.f - s : -s) / Lr[0];
            win[(i & 31) * 256 + j] = g;
        }
        covb[i * 256 + j] = g;
    }
}

// ============================================================================
// z = mu + cov @ eps (unchanged)
// ============================================================================
__global__ __launch_bounds__(256) void zvec_k(
    const float* __restrict__ cov, const float* __restrict__ mu,
    const float* __restrict__ eps, float* __restrict__ z)
{
    __shared__ float es[256];
    const int b = blockIdx.x, i = threadIdx.x;
    es[i] = eps[b * 256 + i];
    __syncthreads();
    const float4* row = (const float4*)(cov + (size_t)b * 65536 + i * 256);
    float s = 0.f;
    #pragma unroll 8
    for (int k = 0; k < 64; k++) {
        float4 v = row[k];
        s = fmaf(v.x, es[4 * k], s);
        s = fmaf(v.y, es[4 * k + 1], s);
        s = fmaf(v.z, es[4 * k + 2], s);
        s = fmaf(v.w, es[4 * k + 3], s);
    }
    z[b * 256 + i] = mu[b * 256 + i] + s;
}

// ============================================================================
// Decoder FC (unchanged)
// ============================================================================
__global__ __launch_bounds__(256) void fc_dec_k(
    const float* __restrict__ z, const float* __restrict__ w,
    const float* __restrict__ bias, float* __restrict__ hd0)
{
    __shared__ float zs[256];
    const int blk = blockIdx.x;
    const int b = blk >> 2;
    const int f = ((blk & 3) << 8) + threadIdx.x;
    zs[threadIdx.x] = z[b * 256 + threadIdx.x];
    __syncthreads();
    const float4* wr = (const float4*)(w + f * 256);
    float s = 0.f;
    #pragma unroll 8
    for (int k = 0; k < 64; k++) {
        float4 v = wr[k];
        s = fmaf(v.x, zs[4 * k], s);
        s = fmaf(v.y, zs[4 * k + 1], s);
        s = fmaf(v.z, zs[4 * k + 2], s);
        s = fmaf(v.w, zs[4 * k + 3], s);
    }
    hd0[b * 1024 + f] = s + bias[f];
}

// ============================================================================
// mu_fix: recompute mu = h @ fc_mu_w^T + b, written LAST in the launch order.
// ============================================================================
__global__ __launch_bounds__(256) void mu_fix(
    const float* __restrict__ h, const float* __restrict__ w,
    const float* __restrict__ bias, float* __restrict__ mu)
{
    __shared__ float hs[1024];
    const int b = blockIdx.x, p = threadIdx.x;
    #pragma unroll
    for (int i = 0; i < 4; i++) hs[p + 256 * i] = h[b * 1024 + p + 256 * i];
    __syncthreads();
    const float4* wr = (const float4*)(w + p * 1024);
    float s = 0.f;
    #pragma unroll 8
    for (int k = 0; k < 256; k++) {
        float4 v = wr[k];
        s = fmaf(v.x, hs[4 * k], s);
        s = fmaf(v.y, hs[4 * k + 1], s);
        s = fmaf(v.z, hs[4 * k + 2], s);
        s = fmaf(v.w, hs[4 * k + 3], s);
    }
    mu[b * 256 + p] = s + bias[p];
}

// ============================================================================
// Decoder v3 (unchanged from R4 — math verified on-device via xr pass)
// ============================================================================
__device__ __forceinline__ float eluf(float v) { return v > 0.f ? v : expf(v) - 1.f; }

template<int PY, int PX, int HIN, int WIN, class F>
__device__ __forceinline__ void for_taps(int ey, int ex, F&& f) {
    if (PY == 0) {
        if (PX == 0) { f(4, ey, ex, true); }
        else         { f(5, ey, ex, true); f(3, ey, ex + 1, ex + 1 < WIN); }
    } else {
        if (PX == 0) { f(7, ey, ex, true); f(1, ey + 1, ex, ey + 1 < HIN); }
        else {
            f(8, ey, ex, true);
            f(6, ey, ex + 1, ex + 1 < WIN);
            f(2, ey + 1, ex, ey + 1 < HIN);
            f(0, ey + 1, ex + 1, (ey + 1 < HIN) && (ex + 1 < WIN));
        }
    }
}

template<int OY>
__device__ __forceinline__ void t4_row(
    const float* __restrict__ wt4t, const float* __restrict__ bt4,
    const float* __restrict__ d1, float* __restrict__ d2, int co)
{
    float a0 = 0.f, a1 = 0.f, a2 = 0.f, a3 = 0.f;
    const float* wb = wt4t + co;
    for (int ci = 0; ci < 64; ci++) {
        const float* base = d1 + ci * 12;
        if (OY % 2 == 0) {
            float4 r = *(const float4*)(base + (OY / 2) * 4);
            float w10 = wb[3 * 4096 + ci * 64];
            float w11 = wb[4 * 4096 + ci * 64];
            float w12 = wb[5 * 4096 + ci * 64];
            a0 = fmaf(r.x, w11, a0);
            a1 = fmaf(r.x, w12, a1); a1 = fmaf(r.y, w10, a1);
            a2 = fmaf(r.y, w11, a2);
            a3 = fmaf(r.y, w12, a3); a3 = fmaf(r.z, w10, a3);
        } else {
            float4 ra = *(const float4*)(base + ((OY - 1) / 2) * 4);
            float4 rb = *(const float4*)(base + ((OY + 1) / 2) * 4);
            float w20 = wb[6 * 4096 + ci * 64], w21 = wb[7 * 4096 + ci * 64], w22 = wb[8 * 4096 + ci * 64];
            float w00 = wb[0 * 4096 + ci * 64], w01 = wb[1 * 4096 + ci * 64], w02 = wb[2 * 4096 + ci * 64];
            a0 = fmaf(ra.x, w21, a0); a0 = fmaf(rb.x, w01, a0);
            a1 = fmaf(ra.x, w22, a1); a1 = fmaf(ra.y, w20, a1);
            a1 = fmaf(rb.x, w02, a1); a1 = fmaf(rb.y, w00, a1);
            a2 = fmaf(ra.y, w21, a2); a2 = fmaf(rb.y, w01, a2);
            a3 = fmaf(ra.y, w22, a3); a3 = fmaf(ra.z, w20, a3);
            a3 = fmaf(rb.y, w02, a3); a3 = fmaf(rb.z, w00, a3);
        }
    }
    float b = bt4[co];
    float4 o = make_float4(eluf(a0 + b), eluf(a1 + b), eluf(a2 + b), eluf(a3 + b));
    *(float4*)(d2 + co * 44 + OY * 8) = o;
}

template<int M>
__device__ __forceinline__ void xrow(float* acc, const float* R, float w0, float w1, float w2)
{
    #pragma unroll
    for (int m = 0; m < M; m++) {
        acc[2 * m]     = fmaf(R[m], w1, acc[2 * m]);
        acc[2 * m + 1] = fmaf(R[m], w2, acc[2 * m + 1]);
        acc[2 * m + 1] = fmaf(R[m + 1], w0, acc[2 * m + 1]);
    }
}

__global__ __launch_bounds__(256) void dec_fused(
    const float* __restrict__ hd0,
    const float* __restrict__ wt5t, const float* __restrict__ bt5,
    const float* __restrict__ wt4t, const float* __restrict__ bt4,
    const float* __restrict__ wt3t, const float* __restrict__ bt3,
    const float* __restrict__ wt2t, const float* __restrict__ bt2,
    const float* __restrict__ wt1,  const float* __restrict__ bt1,
    float* __restrict__ xr)
{
    __shared__ __align__(16) float smem[11776];
    float* d0  = smem;            // 64
    float* d1  = smem + 64;       // [64][3][4] pitch 12
    float* d2  = smem + 832;      // [64][44], rows pitch 8 (5 rows)
    float* scr = smem + 3648;     // [128][20]
    float* d4  = smem;            // [32][260] overlays region A in T2/T1
    float* d3  = smem + 8320;     // [32][108], rows pitch 12 (9 rows)

    const int n = blockIdx.x, tid = threadIdx.x;

    for (int i = tid; i < 3584; i += 256) smem[64 + i] = 0.f;
    for (int i = tid; i < 3456; i += 256) d3[i] = 0.f;
    if (tid < 64) d0[tid] = hd0[n * 64 + tid];
    __syncthreads();

    // T5
    {
        const int co = tid & 63;
        const int wv = __builtin_amdgcn_readfirstlane(tid >> 6);
        const int oy = wv >> 1, ox = wv & 1;
        const int wk = (oy + 1) * 3 + (ox + 1);
        const float* wp = wt5t + wk * 4096 + co;
        float s = bt5[co];
        for (int ci = 0; ci < 64; ci++)
            s = fmaf(d0[ci], wp[ci * 64], s);
        d1[co * 12 + oy * 4 + ox] = eluf(s);
    }
    __syncthreads();

    // T4
    {
        const int co = tid & 63;
        const int oyw = __builtin_amdgcn_readfirstlane(tid >> 6);
        if (oyw == 0)      t4_row<0>(wt4t, bt4, d1, d2, co);
        else if (oyw == 1) t4_row<1>(wt4t, bt4, d1, d2, co);
        else if (oyw == 2) t4_row<2>(wt4t, bt4, d1, d2, co);
        else               t4_row<3>(wt4t, bt4, d1, d2, co);
    }
    __syncthreads();

    // T3
    {
        const int co = tid & 31, pr = (tid >> 5) & 3, cih = tid >> 7;
        const int e = (pr & 1) ? 7 - pr : pr;
        const int o = (pr & 1) ? pr : 7 - pr;
        const int iy_e = e >> 1, iy_o2 = (o - 1) >> 1, iy_o0 = (o + 1) >> 1;
        float acce[8] = {}, acco[8] = {};
        const float* wb = wt3t + co;
        for (int c = 0; c < 32; c++) {
            const int ci = cih * 32 + c;
            const float* base = d2 + ci * 44;
            float re[8], ro2[8], ro0[8];
            *(float4*)(re)      = *(const float4*)(base + iy_e * 8);
            *(float4*)(re + 4)  = *(const float4*)(base + iy_e * 8 + 4);
            *(float4*)(ro2)     = *(const float4*)(base + iy_o2 * 8);
            *(float4*)(ro2 + 4) = *(const float4*)(base + iy_o2 * 8 + 4);
            *(float4*)(ro0)     = *(const float4*)(base + iy_o0 * 8);
            *(float4*)(ro0 + 4) = *(const float4*)(base + iy_o0 * 8 + 4);
            float w10 = wb[3 * 2048 + ci * 32], w11 = wb[4 * 2048 + ci * 32], w12 = wb[5 * 2048 + ci * 32];
            float w20 = wb[6 * 2048 + ci * 32], w21 = wb[7 * 2048 + ci * 32], w22 = wb[8 * 2048 + ci * 32];
            float w00 = wb[0 * 2048 + ci * 32], w01 = wb[1 * 2048 + ci * 32], w02 = wb[2 * 2048 + ci * 32];
            xrow<4>(acce, re, w10, w11, w12);
            xrow<4>(acco, ro2, w20, w21, w22);
            xrow<4>(acco, ro0, w00, w01, w02);
        }
        if (cih == 1) {
            float* s = scr + (tid - 128) * 20;
            #pragma unroll
            for (int k = 0; k < 8; k++) { s[k] = acce[k]; s[8 + k] = acco[k]; }
        }
        __syncthreads();
        if (cih == 0) {
            const float* s = scr + tid * 20;
            const float b = bt3[co];
            float* oe = d3 + co * 108 + e * 12;
            float* oo = d3 + co * 108 + o * 12;
            #pragma unroll
            for (int k = 0; k < 8; k++) {
                oe[k] = eluf(acce[k] + s[k] + b);
                oo[k] = eluf(acco[k] + s[8 + k] + b);
            }
        }
    }
    __syncthreads();

    // T2
    {
        const int co = tid & 31, org = tid >> 5;
        float acc0[16] = {}, acc1[16] = {};
        const float* wb = wt2t + co;
        for (int ci = 0; ci < 32; ci++) {
            const float* base = d3 + ci * 108 + org * 12;
            float A[12], B[12];
            #pragma unroll
            for (int q = 0; q < 3; q++) {
                *(float4*)(A + 4 * q) = *(const float4*)(base + 4 * q);
                *(float4*)(B + 4 * q) = *(const float4*)(base + 12 + 4 * q);
            }
            float w10 = wb[3 * 1024 + ci * 32], w11 = wb[4 * 1024 + ci * 32], w12 = wb[5 * 1024 + ci * 32];
            float w20 = wb[6 * 1024 + ci * 32], w21 = wb[7 * 1024 + ci * 32], w22 = wb[8 * 1024 + ci * 32];
            float w00 = wb[0 * 1024 + ci * 32], w01 = wb[1 * 1024 + ci * 32], w02 = wb[2 * 1024 + ci * 32];
            xrow<8>(acc0, A, w10, w11, w12);
            xrow<8>(acc1, A, w20, w21, w22);
            xrow<8>(acc1, B, w00, w01, w02);
        }
        const float b = bt2[co];
        float* o0 = d4 + co * 260 + (2 * org) * 16;
        float* o1 = o0 + 16;
        #pragma unroll
        for (int q = 0; q < 4; q++) {
            float4 v0 = make_float4(eluf(acc0[4 * q] + b), eluf(acc0[4 * q + 1] + b),
                                    eluf(acc0[4 * q + 2] + b), eluf(acc0[4 * q + 3] + b));
            float4 v1 = make_float4(eluf(acc1[4 * q] + b), eluf(acc1[4 * q + 1] + b),
                                    eluf(acc1[4 * q + 2] + b), eluf(acc1[4 * q + 3] + b));
            *(float4*)(o0 + 4 * q) = v0;
            *(float4*)(o1 + 4 * q) = v1;
        }
    }
    __syncthreads();

    // T1
    {
        const int ey = tid >> 4, ex = tid & 15;
        const float bb = bt1[0];
        float* xi = xr + n * 1024;
        float acc[4] = {};
        for (int ci = 0; ci < 32; ci++) {
            const float* a = d4 + ci * 260;
            const float* w = wt1 + ci * 9;
            for_taps<0, 0, 16, 16>(ey, ex, [&](int wk, int iy, int ix, bool v) {
                acc[0] = fmaf(v ? a[iy * 16 + ix] : 0.f, w[wk], acc[0]); });
            for_taps<0, 1, 16, 16>(ey, ex, [&](int wk, int iy, int ix, bool v) {
                acc[1] = fmaf(v ? a[iy * 16 + ix] : 0.f, w[wk], acc[1]); });
            for_taps<1, 0, 16, 16>(ey, ex, [&](int wk, int iy, int ix, bool v) {
                acc[2] = fmaf(v ? a[iy * 16 + ix] : 0.f, w[wk], acc[2]); });
            for_taps<1, 1, 16, 16>(ey, ex, [&](int wk, int iy, int ix, bool v) {
                acc[3] = fmaf(v ? a[iy * 16 + ix] : 0.f, w[wk], acc[3]); });
        }
        xi[(2 * ey) * 32 + 2 * ex]         = 1.f / (1.f + expf(-(acc[0] + bb)));
        xi[(2 * ey) * 32 + 2 * ex + 1]     = 1.f / (1.f + expf(-(acc[1] + bb)));
        xi[(2 * ey + 1) * 32 + 2 * ex]     = 1.f / (1.f + expf(-(acc[2] + bb)));
        xi[(2 * ey + 1) * 32 + 2 * ex + 1] = 1.f / (1.f + expf(-(acc[3] + bb)));
    }
}

// ============================================================================
extern "C" void kernel_launch(void* const* d_in, const int* in_sizes, int n_in,
                              void* d_out, int out_size, void* d_ws, size_t ws_size,
                              hipStream_t stream)
{
    (void)in_sizes; (void)n_in; (void)out_size; (void)ws_size;
    const float* x    = (const float*)d_in[0];
    const float* eps  = (const float*)d_in[1];
    const float* w1 = (const float*)d_in[2];  const float* b1 = (const float*)d_in[3];
    const float* w2 = (const float*)d_in[4];  const float* b2 = (const float*)d_in[5];
    const float* w3 = (const float*)d_in[6];  const float* b3 = (const float*)d_in[7];
    const float* w4 = (const float*)d_in[8];  const float* b4 = (const float*)d_in[9];
    const float* w5 = (const float*)d_in[10]; const float* b5 = (const float*)d_in[11];
    const float* fc_mu_w = (const float*)d_in[12]; const float* fc_mu_b = (const float*)d_in[13];
    const float* fc_D_w  = (const float*)d_in[14]; const float* fc_D_b  = (const float*)d_in[15];
    const float* fc_B_w  = (const float*)d_in[16]; const float* fc_B_b  = (const float*)d_in[17];
    const float* fc_dec_w = (const float*)d_in[18]; const float* fc_dec_b = (const float*)d_in[19];
    const float* wt5 = (const float*)d_in[20]; const float* bt5 = (const float*)d_in[21];
    const float* wt4 = (const float*)d_in[22]; const float* bt4 = (const float*)d_in[23];
    const float* wt3 = (const float*)d_in[24]; const float* bt3 = (const float*)d_in[25];
    const float* wt2 = (const float*)d_in[26]; const float* bt2 = (const float*)d_in[27];
    const float* wt1 = (const float*)d_in[28]; const float* bt1 = (const float*)d_in[29];

    // workspace layout (floats): total 2,889,728 (~11.6 MB)
    float* ws   = (float*)d_ws;
    float* h    = ws;                  // 262144  [4096][64]
    float* Lb   = ws + 262144;         // 2097152 [256][256][32]
    float* z    = ws + 2359296;        // 65536
    float* hd0  = ws + 2424832;        // 262144  [4096][64]
    float* wt5t = ws + 2686976;        // 36864   [9][64][64]
    float* wt4t = ws + 2723840;        // 36864   [9][64][64]
    float* wt3t = ws + 2760704;        // 18432   [9][64][32]
    float* wt2t = ws + 2779136;        // 9216    [9][32][32]
    float* w2t  = ws + 2788352;        // 9216    [9][32][32]
    float* w3t  = ws + 2797568;        // 18432   [9][32][64]
    float* w4t  = ws + 2816000;        // 36864   [9][64][64]
    float* w5t  = ws + 2852864;        // 36864   [9][64][64]

    // output layout: xr | mu | cov | Pm
    float* out = (float*)d_out;
    float* xr  = out;                 // 4194304
    float* mu  = out + 4194304;       // 65536
    float* cov = out + 4259840;       // 16777216
    float* Pm  = out + 21037056;      // 16777216

    transpose_all8<<<792, 256, 0, stream>>>(wt5, wt4, wt3, wt2, w2, w3, w4, w5,
                                            wt5t, wt4t, wt3t, wt2t, w2t, w3t, w4t, w5t);
    enc_fused<<<4096, 256, 0, stream>>>(x, w1, b1, w2t, b2, w3t, b3, w4t, b4, w5t, b5, h);
    pm_zero<<<16384, 256, 0, stream>>>((float4*)Pm);
    fc_enc<<<dim3(128, 4), 256, 0, stream>>>(h, fc_mu_w, fc_mu_b, fc_D_w, fc_D_b,
                                             fc_B_w, fc_B_b, mu, Pm);
    chol_band<<<256, 64, 0, stream>>>(Pm, Lb);
    inv_band<<<256, 256, 0, stream>>>(Lb, cov);
    zvec_k<<<256, 256, 0, stream>>>(cov, mu, eps, z);
    fc_dec_k<<<1024, 256, 0, stream>>>(z, fc_dec_w, fc_dec_b, hd0);
    dec_fused<<<4096, 256, 0, stream>>>(hd0, wt5t, bt5, wt4t, bt4, wt3t, bt3,
                                        wt2t, bt2, wt1, bt1, xr);
    mu_fix<<<256, 256, 0, stream>>>(h, fc_mu_w, fc_mu_b, mu);
}

// Round 6
// 1229.167 us; speedup vs baseline: 2.7078x; 1.3313x over previous
//
#include <hip/hip_runtime.h>
#include <cmath>

#define ALPHA 0.5f

// ============================================================================
// Weight transpose: conv weights -> [k][ci][co] for coalesced/uniform access.
// Decoder (ConvT) src layout [Cin][Cout][3][3]; encoder (Conv) src [Cout][Cin][3][3].
// ============================================================================
__global__ __launch_bounds__(256) void transpose_all8(
    const float* __restrict__ dw5, const float* __restrict__ dw4,
    const float* __restrict__ dw3, const float* __restrict__ dw2,
    const float* __restrict__ ew2, const float* __restrict__ ew3,
    const float* __restrict__ ew4, const float* __restrict__ ew5,
    float* __restrict__ t5, float* __restrict__ t4,
    float* __restrict__ t3, float* __restrict__ t2,
    float* __restrict__ e2, float* __restrict__ e3,
    float* __restrict__ e4, float* __restrict__ e5)
{
    int idx = blockIdx.x * 256 + threadIdx.x;   // total 202752
    if (idx >= 202752) return;
    const float* w; float* t; int CIN, COUT, loc; bool enc = false;
    if (idx < 36864)       { w = dw5; t = t5; CIN = 64; COUT = 64; loc = idx; }
    else if (idx < 73728)  { w = dw4; t = t4; CIN = 64; COUT = 64; loc = idx - 36864; }
    else if (idx < 92160)  { w = dw3; t = t3; CIN = 64; COUT = 32; loc = idx - 73728; }
    else if (idx < 101376) { w = dw2; t = t2; CIN = 32; COUT = 32; loc = idx - 92160; }
    else if (idx < 110592) { w = ew2; t = e2; CIN = 32; COUT = 32; loc = idx - 101376; enc = true; }
    else if (idx < 129024) { w = ew3; t = e3; CIN = 32; COUT = 64; loc = idx - 110592; enc = true; }
    else if (idx < 165888) { w = ew4; t = e4; CIN = 64; COUT = 64; loc = idx - 129024; enc = true; }
    else                   { w = ew5; t = e5; CIN = 64; COUT = 64; loc = idx - 165888; enc = true; }
    int wk = loc % 9; int r = loc / 9; int ci, co;
    if (enc) { ci = r % CIN;  co = r / CIN;  }   // src [co][ci][k]
    else     { co = r % COUT; ci = r / COUT; }   // src [ci][co][k]
    t[wk * CIN * COUT + ci * COUT + co] = w[loc];
}

// ============================================================================
// Encoder (unchanged)
// ============================================================================
template<int OY, int OX>
__device__ __forceinline__ float c4_cls(
    const float* __restrict__ a3s, const float* __restrict__ w4t,
    float acc, int co)
{
    for (int ci = 0; ci < 64; ci++) {
        #pragma unroll
        for (int ky = 0; ky < 3; ky++) {
            const int iy = 2 * OY - 1 + ky;
            if (iy < 0) continue;
            #pragma unroll
            for (int kx = 0; kx < 3; kx++) {
                const int ix = 2 * OX - 1 + kx;
                if (ix < 0) continue;
                acc = fmaf(a3s[ci * 16 + iy * 4 + ix],
                           w4t[(ky * 3 + kx) * 4096 + ci * 64 + co], acc);
            }
        }
    }
    return acc;
}

__global__ __launch_bounds__(256) void enc_fused(
    const float* __restrict__ x,
    const float* __restrict__ w1,  const float* __restrict__ b1,
    const float* __restrict__ w2t, const float* __restrict__ b2,
    const float* __restrict__ w3t, const float* __restrict__ b3,
    const float* __restrict__ w4t, const float* __restrict__ b4,
    const float* __restrict__ w5t, const float* __restrict__ b5,
    float* __restrict__ hout)
{
    __shared__ __align__(16) float smem[12800];   // 51200 B
    float* a1s  = smem;          // [32][16][18] = 9216 fl
    float* bse  = smem + 9216;   // region B: aliased by phase
    float* imgs = bse;           // phase0: [32][40]
    float* a2s  = bse;           // phase1+: [32][64]
    float* a3s  = bse + 2048;    // [64][16]
    float* a4s  = bse + 3072;    // [64][4]
    float* reds = bse + 3328;    // [4][64]

    const int n = blockIdx.x;
    const int tid = threadIdx.x;

    const float* xi = x + n * 1024;
    #pragma unroll
    for (int i = 0; i < 4; i++) {
        int idx = tid + 256 * i;
        int iy = idx >> 5, ix = idx & 31;
        int col = (ix & 1) ? 20 + (ix >> 1) : (ix >> 1);
        imgs[iy * 40 + col] = xi[idx];
    }
    __syncthreads();

    // conv1
    {
        const int oy = tid >> 4, ox = tid & 15;
        float patch[9];
        #pragma unroll
        for (int ky = 0; ky < 3; ky++) {
            const int iy = 2 * oy - 1 + ky;
            #pragma unroll
            for (int kx = 0; kx < 3; kx++) {
                const int ix = 2 * ox - 1 + kx;
                bool v = (iy >= 0) && (ix >= 0);
                int col = (ix & 1) ? 20 + (ix >> 1) : (ix >> 1);
                patch[ky * 3 + kx] = v ? imgs[iy * 40 + col] : 0.f;
            }
        }
        const int ocol = (ox & 1) ? 9 + (ox >> 1) : (ox >> 1);
        for (int c = 0; c < 32; c++) {
            float acc = b1[c];
            #pragma unroll
            for (int k = 0; k < 9; k++) acc = fmaf(patch[k], w1[c * 9 + k], acc);
            a1s[c * 288 + oy * 18 + ocol] = fmaxf(acc, 0.f);
        }
    }
    __syncthreads();

    // conv2
    {
        const int p = tid & 63, oy = p >> 3, ox = p & 7;
        const int c0u = __builtin_amdgcn_readfirstlane(tid >> 6);
        const int cobase = c0u * 8;
        float acc[8];
        #pragma unroll
        for (int r = 0; r < 8; r++) acc[r] = b2[cobase + r];
        for (int ci = 0; ci < 32; ci++) {
            float patch[9];
            #pragma unroll
            for (int ky = 0; ky < 3; ky++) {
                const int iy = 2 * oy - 1 + ky;
                #pragma unroll
                for (int kx = 0; kx < 3; kx++) {
                    const int ix = 2 * ox - 1 + kx;
                    bool v = (iy >= 0) && (ix >= 0);
                    int col = (ix & 1) ? 9 + (ix >> 1) : (ix >> 1);
                    patch[ky * 3 + kx] = v ? a1s[ci * 288 + iy * 18 + col] : 0.f;
                }
            }
            const float* wci = w2t + ci * 32 + cobase;
            #pragma unroll
            for (int k = 0; k < 9; k++) {
                #pragma unroll
                for (int r = 0; r < 8; r++)
                    acc[r] = fmaf(patch[k], wci[k * 1024 + r], acc[r]);
            }
        }
        __syncthreads();
        #pragma unroll
        for (int r = 0; r < 8; r++)
            a2s[(cobase + r) * 64 + p] = fmaxf(acc[r], 0.f);
    }
    __syncthreads();

    // conv3
    {
        const int px = tid & 15, oy = px >> 2, ox = px & 3;
        const int cg = tid >> 4;
        float4 bv = ((const float4*)b3)[cg];
        float acc[4] = {bv.x, bv.y, bv.z, bv.w};
        for (int ci = 0; ci < 32; ci++) {
            float patch[9];
            #pragma unroll
            for (int ky = 0; ky < 3; ky++) {
                const int iy = 2 * oy - 1 + ky;
                #pragma unroll
                for (int kx = 0; kx < 3; kx++) {
                    const int ix = 2 * ox - 1 + kx;
                    bool v = (iy >= 0) && (ix >= 0);
                    patch[ky * 3 + kx] = v ? a2s[ci * 64 + iy * 8 + ix] : 0.f;
                }
            }
            #pragma unroll
            for (int k = 0; k < 9; k++) {
                float4 wv = *(const float4*)(w3t + k * 2048 + ci * 64 + cg * 4);
                acc[0] = fmaf(patch[k], wv.x, acc[0]);
                acc[1] = fmaf(patch[k], wv.y, acc[1]);
                acc[2] = fmaf(patch[k], wv.z, acc[2]);
                acc[3] = fmaf(patch[k], wv.w, acc[3]);
            }
        }
        #pragma unroll
        for (int r = 0; r < 4; r++)
            a3s[(cg * 4 + r) * 16 + px] = fmaxf(acc[r], 0.f);
    }
    __syncthreads();

    // conv4
    {
        const int co = tid & 63;
        const int cls = __builtin_amdgcn_readfirstlane(tid >> 6);
        float acc = b4[co];
        if (cls == 0)      acc = c4_cls<0, 0>(a3s, w4t, acc, co);
        else if (cls == 1) acc = c4_cls<0, 1>(a3s, w4t, acc, co);
        else if (cls == 2) acc = c4_cls<1, 0>(a3s, w4t, acc, co);
        else               acc = c4_cls<1, 1>(a3s, w4t, acc, co);
        a4s[co * 4 + cls] = fmaxf(acc, 0.f);
    }
    __syncthreads();

    // conv5
    {
        const int c = tid & 63, part = tid >> 6;
        float s = 0.f;
        for (int ci = part * 16; ci < part * 16 + 16; ci++) {
            const float* av = a4s + ci * 4;
            s = fmaf(av[0], w5t[4 * 4096 + ci * 64 + c], s);
            s = fmaf(av[1], w5t[5 * 4096 + ci * 64 + c], s);
            s = fmaf(av[2], w5t[7 * 4096 + ci * 64 + c], s);
            s = fmaf(av[3], w5t[8 * 4096 + ci * 64 + c], s);
        }
        reds[part * 64 + c] = s;
    }
    __syncthreads();
    if (tid < 64) {
        float v = b5[tid] + reds[tid] + reds[64 + tid] + reds[128 + tid] + reds[192 + tid];
        hout[n * 64 + tid] = fmaxf(v, 0.f);
    }
}

// ============================================================================
// Pm zero-fill (unchanged)
// ============================================================================
__global__ __launch_bounds__(256) void pm_zero(float4* __restrict__ Pm4)
{
    Pm4[blockIdx.x * 256 + threadIdx.x] = make_float4(0.f, 0.f, 0.f, 0.f);
}

// ============================================================================
// FC heads (unchanged): mu -> d_out; D/B heads -> Pm directly.
// ============================================================================
__global__ __launch_bounds__(256) void fc_enc(
    const float* __restrict__ h,
    const float* __restrict__ wmu, const float* __restrict__ bmu,
    const float* __restrict__ wD,  const float* __restrict__ bD,
    const float* __restrict__ wB,  const float* __restrict__ bB,
    float* __restrict__ mu, float* __restrict__ Pm)
{
    __shared__ float As[32][65];
    __shared__ float Bs[32][65];
    const int tid = threadIdx.x;
    const int m0 = blockIdx.y * 64;
    const int n0 = blockIdx.x * 64;

    const float* wbase; const float* bias; int nloc; int region;
    if (n0 < 256)       { wbase = wmu; bias = bmu; nloc = n0;        region = 0; }
    else if (n0 < 4352) { wbase = wD;  bias = bD;  nloc = n0 - 256;  region = 1; }
    else                { wbase = wB;  bias = bB;  nloc = n0 - 4352; region = 2; }

    const int tx = tid & 15, ty = tid >> 4;
    float acc[4][4] = {};
    for (int k0 = 0; k0 < 1024; k0 += 32) {
        #pragma unroll
        for (int s = 0; s < 8; s++) {
            int l = tid + 256 * s;
            int row = l >> 5, kk = l & 31;
            As[kk][row] = h[(m0 + row) * 1024 + k0 + kk];
            Bs[kk][row] = wbase[(nloc + row) * 1024 + k0 + kk];
        }
        __syncthreads();
        #pragma unroll
        for (int kk = 0; kk < 32; kk++) {
            float av[4], bv[4];
            #pragma unroll
            for (int i = 0; i < 4; i++) av[i] = As[kk][ty * 4 + i];
            #pragma unroll
            for (int j = 0; j < 4; j++) bv[j] = Bs[kk][tx * 4 + j];
            #pragma unroll
            for (int i = 0; i < 4; i++)
                #pragma unroll
                for (int j = 0; j < 4; j++) acc[i][j] = fmaf(av[i], bv[j], acc[i][j]);
        }
        __syncthreads();
    }
    #pragma unroll
    for (int i = 0; i < 4; i++) {
        int m = m0 + ty * 4 + i;
        size_t pbase = (size_t)m * 65536;
        #pragma unroll
        for (int j = 0; j < 4; j++) {
            int nc = nloc + tx * 4 + j;
            float v = acc[i][j] + bias[nc];
            if (region == 0) {
                mu[m * 256 + nc] = v;
            } else {
                int t = nc >> 8, pi = (nc >> 4) & 15, pj = nc & 15;
                if (region == 1) {
                    int row = t * 16 + pi, col = t * 16 + pj;
                    Pm[pbase + row * 256 + col] = v + (pi == pj ? ALPHA : 0.f);
                } else {
                    int row = (t + 1) * 16 + pi, col = t * 16 + pj;
                    Pm[pbase + row * 256 + col] = v;      // sub-diagonal
                    Pm[pbase + col * 256 + row] = v;      // super-diagonal (transposed)
                }
            }
        }
    }
}

// ============================================================================
// Banded Cholesky (unchanged)
// ============================================================================
__global__ __launch_bounds__(64) void chol_band(
    const float* __restrict__ Pm, float* __restrict__ Lb_g)
{
    __shared__ float Lb[256 * 32];
    __shared__ float Ds[4096];
    __shared__ float Bs2[3840];
    const int b = blockIdx.x, lane = threadIdx.x;
    const float* Pb = Pm + (size_t)b * 65536;
    for (int i = lane; i < 8192; i += 64) Lb[i] = 0.f;
    for (int i = lane; i < 4096; i += 64) {
        int t = i >> 8, r = (i >> 4) & 15, c = i & 15;
        Ds[i] = Pb[(t * 16 + r) * 256 + t * 16 + c];
    }
    for (int i = lane; i < 3840; i += 64) {
        int t = i >> 8, r = (i >> 4) & 15, c = i & 15;
        Bs2[i] = Pb[((t + 1) * 16 + r) * 256 + t * 16 + c];
    }
    __syncthreads();

    const int d = lane;
    for (int j = 0; j < 256; j++) {
        const int i = j + d;
        float s = 0.f;
        if (d < 32 && i < 256) {
            int bi = i >> 4, bj = j >> 4, pi = i & 15, pj = j & 15;
            float a;
            if (bi == bj)           a = Ds[bi * 256 + pi * 16 + pj];
            else if (bi == bj + 1)  a = Bs2[bj * 256 + pi * 16 + pj];
            else                    a = 0.f;
            float s0 = 0.f, s1 = 0.f;
            int kmin = i - 31; if (kmin < 0) kmin = 0;
            int k = kmin;
            for (; k + 1 < j; k += 2) {
                s0 = fmaf(Lb[i * 32 + (i - k)],     Lb[j * 32 + (j - k)],     s0);
                s1 = fmaf(Lb[i * 32 + (i - k - 1)], Lb[j * 32 + (j - k - 1)], s1);
            }
            if (k < j) s0 = fmaf(Lb[i * 32 + (i - k)], Lb[j * 32 + (j - k)], s0);
            s = a - s0 - s1;
        }
        float diag = __shfl(s, 0);
        float Ljj = sqrtf(diag);
        if (d == 0)                  Lb[j * 32] = Ljj;
        else if (d < 32 && i < 256)  Lb[i * 32 + d] = s / Ljj;
        __syncthreads();
    }
    for (int i = lane; i < 8192; i += 64) Lb_g[b * 8192 + i] = Lb[i];
}

// ============================================================================
// cov = inv(L) v2: L-band staged in LDS (wave-uniform broadcast reads),
// 32-deep window in REGISTERS (unroll-by-32 -> static circular indices),
// branchless (zero window slots encode k<j), wave-aligned row skipping.
// ============================================================================
__global__ __launch_bounds__(256) void inv_band(
    const float* __restrict__ Lb_g, float* __restrict__ cov)
{
    __shared__ __align__(16) float Ls[8192];
    __shared__ float rs[256];
    const int b = blockIdx.x, j = threadIdx.x;
    float* covb = cov + (size_t)b * 65536;

    // stage band (float4-coalesced)
    {
        const float4* src = (const float4*)(Lb_g + b * 8192);
        float4* dst = (float4*)Ls;
        #pragma unroll
        for (int q = 0; q < 8; q++) dst[j + 256 * q] = src[j + 256 * q];
    }
    __syncthreads();
    rs[j] = 1.f / Ls[j * 32];
    __syncthreads();

    const int w = __builtin_amdgcn_readfirstlane(j >> 6);
    const int istart = w * 64;                 // 32-aligned, <= any j in wave

    // rows above istart are strictly upper-triangular for this wave -> zero
    for (int i = 0; i < istart; i++) covb[i * 256 + j] = 0.f;

    float g[32];
    #pragma unroll
    for (int q = 0; q < 32; q++) g[q] = 0.f;

    for (int c = istart; c < 256; c += 32) {
        #pragma unroll
        for (int u = 0; u < 32; u++) {
            const int i = c + u;                       // wave-uniform
            const float* Lr = Ls + i * 32;             // broadcast LDS reads
            float s0 = 0.f, s1 = 0.f, s2 = 0.f, s3 = 0.f;
            #pragma unroll
            for (int d = 1; d < 32; d += 4) {
                s0 = fmaf(Lr[d],     g[(u - d) & 31],     s0);
                if (d + 1 < 32) s1 = fmaf(Lr[d + 1], g[(u - d - 1) & 31], s1);
                if (d + 2 < 32) s2 = fmaf(Lr[d + 2], g[(u - d - 2) & 31], s2);
                if (d + 3 < 32) s3 = fmaf(Lr[d + 3], g[(u - d - 3) & 31], s3);
            }
            float s = (s0 + s1) + (s2 + s3);
            float gi = (((i == j) ? 1.f : 0.f) - s) * rs[i];
            g[u & 31] = gi;
            covb[i * 256 + j] = gi;                    // coalesced
        }
    }
}

// ============================================================================
// z = mu + cov @ eps (unchanged)
// ============================================================================
__global__ __launch_bounds__(256) void zvec_k(
    const float* __restrict__ cov, const float* __restrict__ mu,
    const float* __restrict__ eps, float* __restrict__ z)
{
    __shared__ float es[256];
    const int b = blockIdx.x, i = threadIdx.x;
    es[i] = eps[b * 256 + i];
    __syncthreads();
    const float4* row = (const float4*)(cov + (size_t)b * 65536 + i * 256);
    float s = 0.f;
    #pragma unroll 8
    for (int k = 0; k < 64; k++) {
        float4 v = row[k];
        s = fmaf(v.x, es[4 * k], s);
        s = fmaf(v.y, es[4 * k + 1], s);
        s = fmaf(v.z, es[4 * k + 2], s);
        s = fmaf(v.w, es[4 * k + 3], s);
    }
    z[b * 256 + i] = mu[b * 256 + i] + s;
}

// ============================================================================
// Decoder FC (unchanged)
// ============================================================================
__global__ __launch_bounds__(256) void fc_dec_k(
    const float* __restrict__ z, const float* __restrict__ w,
    const float* __restrict__ bias, float* __restrict__ hd0)
{
    __shared__ float zs[256];
    const int blk = blockIdx.x;
    const int b = blk >> 2;
    const int f = ((blk & 3) << 8) + threadIdx.x;
    zs[threadIdx.x] = z[b * 256 + threadIdx.x];
    __syncthreads();
    const float4* wr = (const float4*)(w + f * 256);
    float s = 0.f;
    #pragma unroll 8
    for (int k = 0; k < 64; k++) {
        float4 v = wr[k];
        s = fmaf(v.x, zs[4 * k], s);
        s = fmaf(v.y, zs[4 * k + 1], s);
        s = fmaf(v.z, zs[4 * k + 2], s);
        s = fmaf(v.w, zs[4 * k + 3], s);
    }
    hd0[b * 1024 + f] = s + bias[f];
}

// ============================================================================
// mu_fix (unchanged): recompute mu last.
// ============================================================================
__global__ __launch_bounds__(256) void mu_fix(
    const float* __restrict__ h, const float* __restrict__ w,
    const float* __restrict__ bias, float* __restrict__ mu)
{
    __shared__ float hs[1024];
    const int b = blockIdx.x, p = threadIdx.x;
    #pragma unroll
    for (int i = 0; i < 4; i++) hs[p + 256 * i] = h[b * 1024 + p + 256 * i];
    __syncthreads();
    const float4* wr = (const float4*)(w + p * 1024);
    float s = 0.f;
    #pragma unroll 8
    for (int k = 0; k < 256; k++) {
        float4 v = wr[k];
        s = fmaf(v.x, hs[4 * k], s);
        s = fmaf(v.y, hs[4 * k + 1], s);
        s = fmaf(v.z, hs[4 * k + 2], s);
        s = fmaf(v.w, hs[4 * k + 3], s);
    }
    mu[b * 256 + p] = s + bias[p];
}

// ============================================================================
// Decoder v3 (unchanged)
// ============================================================================
__device__ __forceinline__ float eluf(float v) { return v > 0.f ? v : expf(v) - 1.f; }

template<int PY, int PX, int HIN, int WIN, class F>
__device__ __forceinline__ void for_taps(int ey, int ex, F&& f) {
    if (PY == 0) {
        if (PX == 0) { f(4, ey, ex, true); }
        else         { f(5, ey, ex, true); f(3, ey, ex + 1, ex + 1 < WIN); }
    } else {
        if (PX == 0) { f(7, ey, ex, true); f(1, ey + 1, ex, ey + 1 < HIN); }
        else {
            f(8, ey, ex, true);
            f(6, ey, ex + 1, ex + 1 < WIN);
            f(2, ey + 1, ex, ey + 1 < HIN);
            f(0, ey + 1, ex + 1, (ey + 1 < HIN) && (ex + 1 < WIN));
        }
    }
}

template<int OY>
__device__ __forceinline__ void t4_row(
    const float* __restrict__ wt4t, const float* __restrict__ bt4,
    const float* __restrict__ d1, float* __restrict__ d2, int co)
{
    float a0 = 0.f, a1 = 0.f, a2 = 0.f, a3 = 0.f;
    const float* wb = wt4t + co;
    for (int ci = 0; ci < 64; ci++) {
        const float* base = d1 + ci * 12;
        if (OY % 2 == 0) {
            float4 r = *(const float4*)(base + (OY / 2) * 4);
            float w10 = wb[3 * 4096 + ci * 64];
            float w11 = wb[4 * 4096 + ci * 64];
            float w12 = wb[5 * 4096 + ci * 64];
            a0 = fmaf(r.x, w11, a0);
            a1 = fmaf(r.x, w12, a1); a1 = fmaf(r.y, w10, a1);
            a2 = fmaf(r.y, w11, a2);
            a3 = fmaf(r.y, w12, a3); a3 = fmaf(r.z, w10, a3);
        } else {
            float4 ra = *(const float4*)(base + ((OY - 1) / 2) * 4);
            float4 rb = *(const float4*)(base + ((OY + 1) / 2) * 4);
            float w20 = wb[6 * 4096 + ci * 64], w21 = wb[7 * 4096 + ci * 64], w22 = wb[8 * 4096 + ci * 64];
            float w00 = wb[0 * 4096 + ci * 64], w01 = wb[1 * 4096 + ci * 64], w02 = wb[2 * 4096 + ci * 64];
            a0 = fmaf(ra.x, w21, a0); a0 = fmaf(rb.x, w01, a0);
            a1 = fmaf(ra.x, w22, a1); a1 = fmaf(ra.y, w20, a1);
            a1 = fmaf(rb.x, w02, a1); a1 = fmaf(rb.y, w00, a1);
            a2 = fmaf(ra.y, w21, a2); a2 = fmaf(rb.y, w01, a2);
            a3 = fmaf(ra.y, w22, a3); a3 = fmaf(ra.z, w20, a3);
            a3 = fmaf(rb.y, w02, a3); a3 = fmaf(rb.z, w00, a3);
        }
    }
    float b = bt4[co];
    float4 o = make_float4(eluf(a0 + b), eluf(a1 + b), eluf(a2 + b), eluf(a3 + b));
    *(float4*)(d2 + co * 44 + OY * 8) = o;
}

template<int M>
__device__ __forceinline__ void xrow(float* acc, const float* R, float w0, float w1, float w2)
{
    #pragma unroll
    for (int m = 0; m < M; m++) {
        acc[2 * m]     = fmaf(R[m], w1, acc[2 * m]);
        acc[2 * m + 1] = fmaf(R[m], w2, acc[2 * m + 1]);
        acc[2 * m + 1] = fmaf(R[m + 1], w0, acc[2 * m + 1]);
    }
}

__global__ __launch_bounds__(256) void dec_fused(
    const float* __restrict__ hd0,
    const float* __restrict__ wt5t, const float* __restrict__ bt5,
    const float* __restrict__ wt4t, const float* __restrict__ bt4,
    const float* __restrict__ wt3t, const float* __restrict__ bt3,
    const float* __restrict__ wt2t, const float* __restrict__ bt2,
    const float* __restrict__ wt1,  const float* __restrict__ bt1,
    float* __restrict__ xr)
{
    __shared__ __align__(16) float smem[11776];
    float* d0  = smem;            // 64
    float* d1  = smem + 64;       // [64][3][4] pitch 12
    float* d2  = smem + 832;      // [64][44], rows pitch 8 (5 rows)
    float* scr = smem + 3648;     // [128][20]
    float* d4  = smem;            // [32][260] overlays region A in T2/T1
    float* d3  = smem + 8320;     // [32][108], rows pitch 12 (9 rows)

    const int n = blockIdx.x, tid = threadIdx.x;

    for (int i = tid; i < 3584; i += 256) smem[64 + i] = 0.f;
    for (int i = tid; i < 3456; i += 256) d3[i] = 0.f;
    if (tid < 64) d0[tid] = hd0[n * 64 + tid];
    __syncthreads();

    // T5
    {
        const int co = tid & 63;
        const int wv = __builtin_amdgcn_readfirstlane(tid >> 6);
        const int oy = wv >> 1, ox = wv & 1;
        const int wk = (oy + 1) * 3 + (ox + 1);
        const float* wp = wt5t + wk * 4096 + co;
        float s = bt5[co];
        for (int ci = 0; ci < 64; ci++)
            s = fmaf(d0[ci], wp[ci * 64], s);
        d1[co * 12 + oy * 4 + ox] = eluf(s);
    }
    __syncthreads();

    // T4
    {
        const int co = tid & 63;
        const int oyw = __builtin_amdgcn_readfirstlane(tid >> 6);
        if (oyw == 0)      t4_row<0>(wt4t, bt4, d1, d2, co);
        else if (oyw == 1) t4_row<1>(wt4t, bt4, d1, d2, co);
        else if (oyw == 2) t4_row<2>(wt4t, bt4, d1, d2, co);
        else               t4_row<3>(wt4t, bt4, d1, d2, co);
    }
    __syncthreads();

    // T3
    {
        const int co = tid & 31, pr = (tid >> 5) & 3, cih = tid >> 7;
        const int e = (pr & 1) ? 7 - pr : pr;
        const int o = (pr & 1) ? pr : 7 - pr;
        const int iy_e = e >> 1, iy_o2 = (o - 1) >> 1, iy_o0 = (o + 1) >> 1;
        float acce[8] = {}, acco[8] = {};
        const float* wb = wt3t + co;
        for (int c = 0; c < 32; c++) {
            const int ci = cih * 32 + c;
            const float* base = d2 + ci * 44;
            float re[8], ro2[8], ro0[8];
            *(float4*)(re)      = *(const float4*)(base + iy_e * 8);
            *(float4*)(re + 4)  = *(const float4*)(base + iy_e * 8 + 4);
            *(float4*)(ro2)     = *(const float4*)(base + iy_o2 * 8);
            *(float4*)(ro2 + 4) = *(const float4*)(base + iy_o2 * 8 + 4);
            *(float4*)(ro0)     = *(const float4*)(base + iy_o0 * 8);
            *(float4*)(ro0 + 4) = *(const float4*)(base + iy_o0 * 8 + 4);
            float w10 = wb[3 * 2048 + ci * 32], w11 = wb[4 * 2048 + ci * 32], w12 = wb[5 * 2048 + ci * 32];
            float w20 = wb[6 * 2048 + ci * 32], w21 = wb[7 * 2048 + ci * 32], w22 = wb[8 * 2048 + ci * 32];
            float w00 = wb[0 * 2048 + ci * 32], w01 = wb[1 * 2048 + ci * 32], w02 = wb[2 * 2048 + ci * 32];
            xrow<4>(acce, re, w10, w11, w12);
            xrow<4>(acco, ro2, w20, w21, w22);
            xrow<4>(acco, ro0, w00, w01, w02);
        }
        if (cih == 1) {
            float* s = scr + (tid - 128) * 20;
            #pragma unroll
            for (int k = 0; k < 8; k++) { s[k] = acce[k]; s[8 + k] = acco[k]; }
        }
        __syncthreads();
        if (cih == 0) {
            const float* s = scr + tid * 20;
            const float b = bt3[co];
            float* oe = d3 + co * 108 + e * 12;
            float* oo = d3 + co * 108 + o * 12;
            #pragma unroll
            for (int k = 0; k < 8; k++) {
                oe[k] = eluf(acce[k] + s[k] + b);
                oo[k] = eluf(acco[k] + s[8 + k] + b);
            }
        }
    }
    __syncthreads();

    // T2
    {
        const int co = tid & 31, org = tid >> 5;
        float acc0[16] = {}, acc1[16] = {};
        const float* wb = wt2t + co;
        for (int ci = 0; ci < 32; ci++) {
            const float* base = d3 + ci * 108 + org * 12;
            float A[12], B[12];
            #pragma unroll
            for (int q = 0; q < 3; q++) {
                *(float4*)(A + 4 * q) = *(const float4*)(base + 4 * q);
                *(float4*)(B + 4 * q) = *(const float4*)(base + 12 + 4 * q);
            }
            float w10 = wb[3 * 1024 + ci * 32], w11 = wb[4 * 1024 + ci * 32], w12 = wb[5 * 1024 + ci * 32];
            float w20 = wb[6 * 1024 + ci * 32], w21 = wb[7 * 1024 + ci * 32], w22 = wb[8 * 1024 + ci * 32];
            float w00 = wb[0 * 1024 + ci * 32], w01 = wb[1 * 1024 + ci * 32], w02 = wb[2 * 1024 + ci * 32];
            xrow<8>(acc0, A, w10, w11, w12);
            xrow<8>(acc1, A, w20, w21, w22);
            xrow<8>(acc1, B, w00, w01, w02);
        }
        const float b = bt2[co];
        float* o0 = d4 + co * 260 + (2 * org) * 16;
        float* o1 = o0 + 16;
        #pragma unroll
        for (int q = 0; q < 4; q++) {
            float4 v0 = make_float4(eluf(acc0[4 * q] + b), eluf(acc0[4 * q + 1] + b),
                                    eluf(acc0[4 * q + 2] + b), eluf(acc0[4 * q + 3] + b));
            float4 v1 = make_float4(eluf(acc1[4 * q] + b), eluf(acc1[4 * q + 1] + b),
                                    eluf(acc1[4 * q + 2] + b), eluf(acc1[4 * q + 3] + b));
            *(float4*)(o0 + 4 * q) = v0;
            *(float4*)(o1 + 4 * q) = v1;
        }
    }
    __syncthreads();

    // T1
    {
        const int ey = tid >> 4, ex = tid & 15;
        const float bb = bt1[0];
        float* xi = xr + n * 1024;
        float acc[4] = {};
        for (int ci = 0; ci < 32; ci++) {
            const float* a = d4 + ci * 260;
            const float* w = wt1 + ci * 9;
            for_taps<0, 0, 16, 16>(ey, ex, [&](int wk, int iy, int ix, bool v) {
                acc[0] = fmaf(v ? a[iy * 16 + ix] : 0.f, w[wk], acc[0]); });
            for_taps<0, 1, 16, 16>(ey, ex, [&](int wk, int iy, int ix, bool v) {
                acc[1] = fmaf(v ? a[iy * 16 + ix] : 0.f, w[wk], acc[1]); });
            for_taps<1, 0, 16, 16>(ey, ex, [&](int wk, int iy, int ix, bool v) {
                acc[2] = fmaf(v ? a[iy * 16 + ix] : 0.f, w[wk], acc[2]); });
            for_taps<1, 1, 16, 16>(ey, ex, [&](int wk, int iy, int ix, bool v) {
                acc[3] = fmaf(v ? a[iy * 16 + ix] : 0.f, w[wk], acc[3]); });
        }
        xi[(2 * ey) * 32 + 2 * ex]         = 1.f / (1.f + expf(-(acc[0] + bb)));
        xi[(2 * ey) * 32 + 2 * ex + 1]     = 1.f / (1.f + expf(-(acc[1] + bb)));
        xi[(2 * ey + 1) * 32 + 2 * ex]     = 1.f / (1.f + expf(-(acc[2] + bb)));
        xi[(2 * ey + 1) * 32 + 2 * ex + 1] = 1.f / (1.f + expf(-(acc[3] + bb)));
    }
}

// ============================================================================
extern "C" void kernel_launch(void* const* d_in, const int* in_sizes, int n_in,
                              void* d_out, int out_size, void* d_ws, size_t ws_size,
                              hipStream_t stream)
{
    (void)in_sizes; (void)n_in; (void)out_size; (void)ws_size;
    const float* x    = (const float*)d_in[0];
    const float* eps  = (const float*)d_in[1];
    const float* w1 = (const float*)d_in[2];  const float* b1 = (const float*)d_in[3];
    const float* w2 = (const float*)d_in[4];  const float* b2 = (const float*)d_in[5];
    const float* w3 = (const float*)d_in[6];  const float* b3 = (const float*)d_in[7];
    const float* w4 = (const float*)d_in[8];  const float* b4 = (const float*)d_in[9];
    const float* w5 = (const float*)d_in[10]; const float* b5 = (const float*)d_in[11];
    const float* fc_mu_w = (const float*)d_in[12]; const float* fc_mu_b = (const float*)d_in[13];
    const float* fc_D_w  = (const float*)d_in[14]; const float* fc_D_b  = (const float*)d_in[15];
    const float* fc_B_w  = (const float*)d_in[16]; const float* fc_B_b  = (const float*)d_in[17];
    const float* fc_dec_w = (const float*)d_in[18]; const float* fc_dec_b = (const float*)d_in[19];
    const float* wt5 = (const float*)d_in[20]; const float* bt5 = (const float*)d_in[21];
    const float* wt4 = (const float*)d_in[22]; const float* bt4 = (const float*)d_in[23];
    const float* wt3 = (const float*)d_in[24]; const float* bt3 = (const float*)d_in[25];
    const float* wt2 = (const float*)d_in[26]; const float* bt2 = (const float*)d_in[27];
    const float* wt1 = (const float*)d_in[28]; const float* bt1 = (const float*)d_in[29];

    // workspace layout (floats): total 2,889,728 (~11.6 MB)
    float* ws   = (float*)d_ws;
    float* h    = ws;                  // 262144  [4096][64]
    float* Lb   = ws + 262144;         // 2097152 [256][256][32]
    float* z    = ws + 2359296;        // 65536
    float* hd0  = ws + 2424832;        // 262144  [4096][64]
    float* wt5t = ws + 2686976;        // 36864   [9][64][64]
    float* wt4t = ws + 2723840;        // 36864   [9][64][64]
    float* wt3t = ws + 2760704;        // 18432   [9][64][32]
    float* wt2t = ws + 2779136;        // 9216    [9][32][32]
    float* w2t  = ws + 2788352;        // 9216    [9][32][32]
    float* w3t  = ws + 2797568;        // 18432   [9][32][64]
    float* w4t  = ws + 2816000;        // 36864   [9][64][64]
    float* w5t  = ws + 2852864;        // 36864   [9][64][64]

    // output layout: xr | mu | cov | Pm
    float* out = (float*)d_out;
    float* xr  = out;                 // 4194304
    float* mu  = out + 4194304;       // 65536
    float* cov = out + 4259840;       // 16777216
    float* Pm  = out + 21037056;      // 16777216

    transpose_all8<<<792, 256, 0, stream>>>(wt5, wt4, wt3, wt2, w2, w3, w4, w5,
                                            wt5t, wt4t, wt3t, wt2t, w2t, w3t, w4t, w5t);
    enc_fused<<<4096, 256, 0, stream>>>(x, w1, b1, w2t, b2, w3t, b3, w4t, b4, w5t, b5, h);
    pm_zero<<<16384, 256, 0, stream>>>((float4*)Pm);
    fc_enc<<<dim3(128, 4), 256, 0, stream>>>(h, fc_mu_w, fc_mu_b, fc_D_w, fc_D_b,
                                             fc_B_w, fc_B_b, mu, Pm);
    chol_band<<<256, 64, 0, stream>>>(Pm, Lb);
    inv_band<<<256, 256, 0, stream>>>(Lb, cov);
    zvec_k<<<256, 256, 0, stream>>>(cov, mu, eps, z);
    fc_dec_k<<<1024, 256, 0, stream>>>(z, fc_dec_w, fc_dec_b, hd0);
    dec_fused<<<4096, 256, 0, stream>>>(hd0, wt5t, bt5, wt4t, bt4, wt3t, bt3,
                                        wt2t, bt2, wt1, bt1, xr);
    mu_fix<<<256, 256, 0, stream>>>(h, fc_mu_w, fc_mu_b, mu);
}